// Round 15
// baseline (427.535 us; speedup 1.0000x reference)
//
#include <hip/hip_runtime.h>
#include <hip/hip_bf16.h>

#define B_ 2
#define CIN 128
#define HIN 91
#define WIN 180
#define NIN (HIN*WIN)         // 16380
#define COUT_ 64
#define HOUT 181
#define WOUT 360
#define NOUT (HOUT*WOUT)      // 65160
#define KK 9
#define NNZ_ (NOUT*8)         // 521280
#define CTOT 128
#define NH 4
#define HD 32
#define EPS_ 1e-5f
#define PTOT ((size_t)B_*NOUT)   // 130320
#define BCAP 40

// q pre-scale: 1/sqrt(32) * log2(e)  -> scores are in log2 domain; softmax uses exp2
#define QSCALE (0.17677669529663688f * 1.4426950408889634f)

typedef short s16x8 __attribute__((ext_vector_type(8)));
typedef float f32x4v __attribute__((ext_vector_type(4)));
typedef float f32x16v __attribute__((ext_vector_type(16)));
typedef int i32x2v __attribute__((ext_vector_type(2)));

// workspace layout (float offsets)
// h is bf16 [PTOT][128] (33.4 MB) in the OFF_H region.
#define OFF_Q  ((size_t)0)
#define OFF_K  ((size_t)8340480)
#define OFF_WOT ((size_t)16680960)                   // wot bf16 [128][128]
#define OFF_H  ((size_t)18869760)
#define OFF_S1 (OFF_H + (size_t)B_*NOUT*CTOT)        // 35550720
#define OFF_S2 (OFF_S1 + 32)
#define OFF_WT (OFF_S2 + 32)                         // wtb bf16 [K][64][128]
#define OFF_VT (OFF_WT + (size_t)KK*CIN*COUT_)       // vt bf16 spans [35624512, 43964992)
#define OFF_CNT OFF_VT                               // 65536 ints (aliases vt; dead before kQKV)
#define OFF_CSR (OFF_VT + 65536)                     // NOUT*BCAP uint2 (aliases vt; dead before kQKV)

__device__ inline ushort f2b(float x) { return __bfloat16_as_ushort(__float2bfloat16(x)); }
__device__ inline float b2f(ushort u) { return __bfloat162float(__ushort_as_bfloat16(u)); }
__device__ inline uint pk2(float lo, float hi) {
    return (uint)f2b(lo) | ((uint)f2b(hi) << 16);
}

// ---------------- kT: weight transposes (one-shot) -------------------------------------------
__global__ __launch_bounds__(256) void kT(const float* __restrict__ wd, const float* __restrict__ wqkv,
                                          const float* __restrict__ wo, ushort* __restrict__ wtb,
                                          ushort* __restrict__ wqt, ushort* __restrict__ wot) {
    int idx = blockIdx.x * 256 + threadIdx.x;
    if (idx < KK * CIN * COUT_) {
        int cin = idx & 127;
        int rest = idx >> 7;
        int cout = rest & 63;
        int k = rest >> 6;
        wtb[idx] = f2b(wd[((size_t)cout * CIN + cin) * KK + k]);
    } else if (idx < KK * CIN * COUT_ + 384 * 128) {
        int i2 = idx - KK * CIN * COUT_;
        int n = i2 >> 7, kk = i2 & 127;
        float v = wqkv[(size_t)kk * 384 + n];
        if (n < 128) v *= QSCALE;   // fold q-scale * log2(e)
        wqt[i2] = f2b(v);
    } else {
        int i3 = idx - (KK * CIN * COUT_ + 384 * 128);
        if (i3 < 128 * 128) {
            int n = i3 >> 7, kk = i3 & 127;
            wot[i3] = f2b(wo[(size_t)kk * 128 + n]);
        }
    }
}

// ---------------- kA v2 (MFMA): xw[k][n][b][cout] = bf16( (x*quad) @ wt[k] ) -----------------
__global__ __launch_bounds__(256) void kA(const float* __restrict__ x, const ushort* __restrict__ wtb,
                                          const float* __restrict__ quad, ushort* __restrict__ xw) {
    __shared__ ushort As[128][128];              // 32 KB, swizzled: A rows = n, cols = cin
    __shared__ __align__(16) char buf[16384];    // union: f32 strip tmp / Bs / bounce
    ushort (*Bs)[128] = reinterpret_cast<ushort(*)[128]>(buf);
    ushort (*Bo)[64]  = reinterpret_cast<ushort(*)[64]>(buf);
    float  (*tmp)[17] = reinterpret_cast<float(*)[17]>(buf);
    int tid = threadIdx.x;
    int n0 = blockIdx.x * 128;
    int b  = blockIdx.y;
    const float* xb = x + (size_t)b * CIN * NIN;
    for (int s = 0; s < 8; ++s) {
        int nbase = n0 + s * 16;
        for (int idx = tid; idx < 128 * 16; idx += 256) {
            int cin = idx >> 4, nn = idx & 15;
            int n = nbase + nn;
            tmp[cin][nn] = (n < NIN) ? xb[(size_t)cin * NIN + n] : 0.f;
        }
        __syncthreads();
        {
            int rl = tid >> 4, c8 = tid & 15;
            int n = nbase + rl;
            float qd = (n < NIN) ? quad[n / WIN] : 0.f;
            ushort w8[8];
            #pragma unroll
            for (int i = 0; i < 8; ++i) w8[i] = f2b(tmp[c8 * 8 + i][rl] * qd);
            int row = s * 16 + rl;
            *reinterpret_cast<uint4*>(&As[row][(c8 ^ (row & 7)) * 8]) = *reinterpret_cast<const uint4*>(w8);
        }
        __syncthreads();
    }
    int w = tid >> 6, lane = tid & 63;
    int l16 = lane & 15, kh = lane >> 4;
    int sa = l16 & 7;
    for (int k = 0; k < KK; ++k) {
        __syncthreads();
        for (int i = tid; i < 1024; i += 256) {
            int rl = i >> 4, c8 = i & 15;
            uint4 v = *reinterpret_cast<const uint4*>(wtb + (((size_t)k * 64 + rl) << 7) + c8 * 8);
            *reinterpret_cast<uint4*>(&Bs[rl][(c8 ^ (rl & 7)) * 8]) = v;
        }
        __syncthreads();
        f32x4v acc[2][4];
        #pragma unroll
        for (int mi = 0; mi < 2; ++mi)
            #pragma unroll
            for (int nf = 0; nf < 4; ++nf) { acc[mi][nf][0] = 0; acc[mi][nf][1] = 0; acc[mi][nf][2] = 0; acc[mi][nf][3] = 0; }
        #pragma unroll
        for (int ks = 0; ks < 4; ++ks) {
            int c8 = ks * 4 + kh;
            s16x8 a0 = *reinterpret_cast<const s16x8*>(&As[w * 32 + l16][(c8 ^ sa) * 8]);
            s16x8 a1 = *reinterpret_cast<const s16x8*>(&As[w * 32 + 16 + l16][(c8 ^ sa) * 8]);
            #pragma unroll
            for (int nf = 0; nf < 4; ++nf) {
                int nn = nf * 16 + l16;
                s16x8 bf = *reinterpret_cast<const s16x8*>(&Bs[nn][(c8 ^ (nn & 7)) * 8]);
                acc[0][nf] = __builtin_amdgcn_mfma_f32_16x16x32_bf16(a0, bf, acc[0][nf], 0, 0, 0);
                acc[1][nf] = __builtin_amdgcn_mfma_f32_16x16x32_bf16(a1, bf, acc[1][nf], 0, 0, 0);
            }
        }
        __syncthreads();
        #pragma unroll
        for (int mi = 0; mi < 2; ++mi) {
            #pragma unroll
            for (int nf = 0; nf < 4; ++nf) {
                int col = nf * 16 + l16;
                #pragma unroll
                for (int j = 0; j < 4; ++j) {
                    int rowl = w * 32 + mi * 16 + kh * 4 + j;
                    Bo[rowl][((col >> 3) ^ (rowl & 7)) * 8 + (col & 7)] = f2b(acc[mi][nf][j]);
                }
            }
        }
        __syncthreads();
        for (int i = tid; i < 1024; i += 256) {
            int rl = i >> 3, u = i & 7;
            int n = n0 + rl;
            if (n < NIN) {
                uint4 v = *reinterpret_cast<const uint4*>(&Bo[rl][(u ^ (rl & 7)) * 8]);
                *reinterpret_cast<uint4*>(xw + (((size_t)(k * NIN + n) * 2 + b) << 6) + u * 8) = v;
            }
        }
    }
}

// ---------------- kFill: bucket entries by output row ----------------------------------------
__global__ __launch_bounds__(256) void kFill(const int* __restrict__ row, const int* __restrict__ col,
                                             const int* __restrict__ ker, const float* __restrict__ psi,
                                             int* __restrict__ cnt, uint2* __restrict__ csr) {
    int e = blockIdx.x * 256 + threadIdx.x;
    if (e >= NNZ_) return;
    int r = row[e];
    int pos = atomicAdd(&cnt[r], 1);
    if (pos < BCAP) {
        uint2 pl;
        pl.x = (uint)col[e] | ((uint)ker[e] << 20);
        pl.y = __float_as_uint(psi[e]);
        csr[(size_t)r * BCAP + pos] = pl;
    }
}

// ---------------- kGather: h (bf16) ch0-63 = sum psi*xw ; fused GN1 stats --------------------
#define GGRID 2037
__global__ __launch_bounds__(256) void kGather(const uint* __restrict__ xw, const int* __restrict__ cnt,
                                               const uint2* __restrict__ csr, ushort* __restrict__ h16,
                                               const float* __restrict__ bd, float* __restrict__ s1) {
    int lane = threadIdx.x & 63;
    int wv = threadIdx.x >> 6;
    int b = lane >> 5;        // batch
    int c2 = lane & 31;       // cout pair index (couts 2*c2, 2*c2+1)
    float2 bdv = *reinterpret_cast<const float2*>(&bd[c2 * 2]);
    float sA = 0.f, qA = 0.f;
    uint* hw = reinterpret_cast<uint*>(h16);
    for (int r = blockIdx.x * 4 + wv; r < NOUT; r += GGRID * 4) {
        int n = min(cnt[r], BCAP);
        float a0 = 0.f, a1 = 0.f;
        const uint2* bucket = csr + (size_t)r * BCAP;
        for (int i = 0; i < n; ++i) {
            uint2 pl = bucket[i];
            int c = pl.x & 0xFFFFF;
            int kk = pl.x >> 20;
            float p = __uint_as_float(pl.y);
            uint v = xw[((size_t)kk * NIN + c) * 64 + lane];
            a0 = fmaf(p, b2f((ushort)(v & 0xFFFF)), a0);
            a1 = fmaf(p, b2f((ushort)(v >> 16)), a1);
        }
        hw[((size_t)b * NOUT + r) * 64 + c2] = pk2(a0, a1);
        float y0 = a0 + bdv.x, y1 = a1 + bdv.y;
        sA += y0 + y1; qA += y0 * y0 + y1 * y1;
    }
    #pragma unroll
    for (int o = 1; o <= 2; o <<= 1) { sA += __shfl_xor(sA, o); qA += __shfl_xor(qA, o); }
    __shared__ float red[4][2][8][2];
    if ((lane & 3) == 0) {
        red[wv][b][c2 >> 2][0] = sA;
        red[wv][b][c2 >> 2][1] = qA;
    }
    __syncthreads();
    if (threadIdx.x < 32) {
        int bb = threadIdx.x >> 4, g = (threadIdx.x >> 1) & 7, isq = threadIdx.x & 1;
        float v = red[0][bb][g][isq] + red[1][bb][g][isq] + red[2][bb][g][isq] + red[3][bb][g][isq];
        atomicAdd(&s1[(bb * 8 + g) * 2 + isq], v);
    }
}

// ---------------- kSkip: transpose skip into h (bf16) ch64..127; fused GN2 stats 4..7 --------
__global__ void kSkip(const float* __restrict__ skip, ushort* __restrict__ h16, float* __restrict__ s2) {
    __shared__ float tile[32][33];
    __shared__ float acc4[4];
    int c0 = blockIdx.y * 32, b = blockIdx.z;
    int tx = threadIdx.x, ty = threadIdx.y;
    int tid = ty * 32 + tx;
    if (tid < 4) acc4[tid] = 0.f;
    float sA[2] = {0.f, 0.f}, qA[2] = {0.f, 0.f};
    uint* hw = reinterpret_cast<uint*>(h16);
    for (int n0 = blockIdx.x * 32; n0 < NOUT; n0 += 256 * 32) {
        #pragma unroll
        for (int j = 0; j < 4; ++j) {
            int c = c0 + ty + j * 8, n = n0 + tx;
            if (n < NOUT) {
                float v = skip[((size_t)b * 64 + c) * NOUT + n];
                tile[ty + j * 8][tx] = v;
                int gi = (ty + 8 * j) >> 4;
                sA[gi] += v; qA[gi] += v * v;
            }
        }
        __syncthreads();
        for (int idx = tid; idx < 512; idx += 256) {   // 32 n x 16 channel-pairs
            int nn = idx >> 4, cp = idx & 15;
            int n = n0 + nn;
            if (n < NOUT) {
                uint st = pk2(tile[cp * 2][nn], tile[cp * 2 + 1][nn]);
                hw[((size_t)b * NOUT + n) * 64 + 32 + (c0 >> 1) + cp] = st;   // ch 64+c0+2cp
            }
        }
        __syncthreads();
    }
    atomicAdd(&acc4[0], sA[0]); atomicAdd(&acc4[1], qA[0]);
    atomicAdd(&acc4[2], sA[1]); atomicAdd(&acc4[3], qA[1]);
    __syncthreads();
    if (tid < 4) {
        int gi = tid >> 1, isq = tid & 1;
        int g = 4 + (c0 >> 4) + gi;
        atomicAdd(&s2[(b * 8 + g) * 2 + isq], acc4[tid]);
    }
}

// ---------------- kApply1: GN1 + GELU in place (bf16 h); fused GN2 stats groups 0..3 ---------
#define AGRID 2048
__global__ __launch_bounds__(256) void kApply1(ushort* __restrict__ h16, const float* __restrict__ bd,
                                               const float* __restrict__ g1, const float* __restrict__ b1,
                                               const float* __restrict__ s1, float* __restrict__ s2) {
    int tid = threadIdx.x;
    int c8g = tid & 7;
    int lane = tid & 63, wv = tid >> 6;
    const float invc = 1.0f / (8.0f * NOUT);
    float mu0 = s1[c8g * 2] * invc;
    float r0 = rsqrtf(s1[c8g * 2 + 1] * invc - mu0 * mu0 + EPS_);
    float mu1 = s1[(8 + c8g) * 2] * invc;
    float r1 = rsqrtf(s1[(8 + c8g) * 2 + 1] * invc - mu1 * mu1 + EPS_);
    float bdv[8], g1v[8], b1v[8];
    #pragma unroll
    for (int j = 0; j < 8; ++j) {
        int c = c8g * 8 + j;
        bdv[j] = bd[c]; g1v[j] = g1[c]; b1v[j] = b1[c];
    }
    float sA[2] = {0.f, 0.f}, qA[2] = {0.f, 0.f};
    const size_t total = (size_t)B_ * NOUT * 8;
    uint4* hb = reinterpret_cast<uint4*>(h16);
    for (size_t idx = (size_t)blockIdx.x * 256 + tid; idx < total; idx += (size_t)AGRID * 256) {
        size_t pn = idx >> 3;
        int b = pn >= (size_t)NOUT;
        float mu = b ? mu1 : mu0, rstd = b ? r1 : r0;
        uint4* p = hb + pn * 16 + c8g;
        uint4 hv = *p;
        const ushort* hs = reinterpret_cast<const ushort*>(&hv);
        float ls = 0.f, lq = 0.f;
        uint outw[4];
        #pragma unroll
        for (int jp = 0; jp < 4; ++jp) {
            float a0 = b2f(hs[jp * 2]) + bdv[jp * 2];
            float a1 = b2f(hs[jp * 2 + 1]) + bdv[jp * 2 + 1];
            float t0 = (a0 - mu) * rstd * g1v[jp * 2] + b1v[jp * 2];
            float t1 = (a1 - mu) * rstd * g1v[jp * 2 + 1] + b1v[jp * 2 + 1];
            float ge0 = t0 * 0.5f * (1.0f + erff(t0 * 0.70710678118654752f));
            float ge1 = t1 * 0.5f * (1.0f + erff(t1 * 0.70710678118654752f));
            ls += ge0 + ge1; lq += ge0 * ge0 + ge1 * ge1;
            outw[jp] = pk2(ge0, ge1);
        }
        sA[b] += ls; qA[b] += lq;
        uint4 st = {outw[0], outw[1], outw[2], outw[3]};
        *p = st;
    }
    #pragma unroll
    for (int o = 8; o <= 32; o <<= 1) {
        sA[0] += __shfl_xor(sA[0], o); qA[0] += __shfl_xor(qA[0], o);
        sA[1] += __shfl_xor(sA[1], o); qA[1] += __shfl_xor(qA[1], o);
    }
    sA[0] += __shfl_xor(sA[0], 1); qA[0] += __shfl_xor(qA[0], 1);
    sA[1] += __shfl_xor(sA[1], 1); qA[1] += __shfl_xor(qA[1], 1);
    __shared__ float red[4][4][4];
    if (lane < 8 && !(lane & 1)) {
        int g = lane >> 1;
        red[wv][g][0] = sA[0]; red[wv][g][1] = qA[0];
        red[wv][g][2] = sA[1]; red[wv][g][3] = qA[1];
    }
    __syncthreads();
    if (tid < 16) {
        int g = tid >> 2, q = tid & 3;
        float v = red[0][g][q] + red[1][g][q] + red[2][g][q] + red[3][g][q];
        int b = q >> 1, isq = q & 1;
        atomicAdd(&s2[(b * 8 + g) * 2 + isq], v);
    }
}

// ---------------- kQKV: one h pass (bf16), swizzled LDS, 3 output chunks ---------------------
__global__ __launch_bounds__(256) void kQKV(const ushort* __restrict__ h16, const ushort* __restrict__ wqt,
                                            const float* __restrict__ bqkv, const float* __restrict__ g2,
                                            const float* __restrict__ b2, const float* __restrict__ s2,
                                            ushort* __restrict__ qg, ushort* __restrict__ kg,
                                            ushort* __restrict__ vtg) {
    __shared__ ushort As[128][128];
    __shared__ ushort Bs[128][128];
    __shared__ float muT[16], rsT[16], g2T[128], b2T[128];
    int tid = threadIdx.x;
    size_t r0 = (size_t)blockIdx.x * 128;
    const float invc2 = 1.0f / (16.0f * NOUT);
    if (tid < 16) {
        float mu = s2[tid * 2] * invc2;
        float ex2 = s2[tid * 2 + 1] * invc2;
        muT[tid] = mu;
        rsT[tid] = rsqrtf(ex2 - mu * mu + EPS_);
    }
    if (tid < 128) { g2T[tid] = g2[tid]; b2T[tid] = b2[tid]; }
    __syncthreads();
    const uint4* hb = reinterpret_cast<const uint4*>(h16);
    for (int i = tid; i < 2048; i += 256) {
        int rl = i >> 4, c8 = i & 15;
        size_t rg = r0 + rl;
        uint4 wv = {0, 0, 0, 0};
        if (rg < PTOT) {
            int c = c8 * 8;
            int g = ((rg >= (size_t)NOUT) ? 8 : 0) + (c >> 4);
            float mu = muT[g], rs = rsT[g];
            uint4 hv = hb[rg * 16 + c8];
            const ushort* hs = reinterpret_cast<const ushort*>(&hv);
            float t[8];
            #pragma unroll
            for (int j = 0; j < 8; ++j)
                t[j] = (b2f(hs[j]) - mu) * rs * g2T[c + j] + b2T[c + j];
            wv.x = pk2(t[0], t[1]); wv.y = pk2(t[2], t[3]);
            wv.z = pk2(t[4], t[5]); wv.w = pk2(t[6], t[7]);
        }
        *reinterpret_cast<uint4*>(&As[rl][(c8 ^ (rl & 7)) * 8]) = wv;
    }
    int w = tid >> 6, lane = tid & 63;
    int l16 = lane & 15, kh = lane >> 4;
    int sa = l16 & 7;
    for (int n0 = 0; n0 < 384; n0 += 128) {
        __syncthreads();
        for (int i = tid; i < 2048; i += 256) {
            int rl = i >> 4, c8 = i & 15;
            uint4 v = *reinterpret_cast<const uint4*>(wqt + ((size_t)(n0 + rl) << 7) + c8 * 8);
            *reinterpret_cast<uint4*>(&Bs[rl][(c8 ^ (rl & 7)) * 8]) = v;
        }
        __syncthreads();
        f32x4v acc[2][8];
        #pragma unroll
        for (int mi = 0; mi < 2; ++mi)
            #pragma unroll
            for (int nf = 0; nf < 8; ++nf) { acc[mi][nf][0] = 0; acc[mi][nf][1] = 0; acc[mi][nf][2] = 0; acc[mi][nf][3] = 0; }
        #pragma unroll
        for (int ks = 0; ks < 4; ++ks) {
            int c8 = ks * 4 + kh;
            s16x8 a0 = *reinterpret_cast<const s16x8*>(&As[w * 32 + l16][(c8 ^ sa) * 8]);
            s16x8 a1 = *reinterpret_cast<const s16x8*>(&As[w * 32 + 16 + l16][(c8 ^ sa) * 8]);
            #pragma unroll
            for (int nf = 0; nf < 8; ++nf) {
                int nn = nf * 16 + l16;
                s16x8 bf = *reinterpret_cast<const s16x8*>(&Bs[nn][(c8 ^ (nn & 7)) * 8]);
                acc[0][nf] = __builtin_amdgcn_mfma_f32_16x16x32_bf16(a0, bf, acc[0][nf], 0, 0, 0);
                acc[1][nf] = __builtin_amdgcn_mfma_f32_16x16x32_bf16(a1, bf, acc[1][nf], 0, 0, 0);
            }
        }
        if (n0 < 256) {
            __syncthreads();
            const float bscale = (n0 == 0) ? QSCALE : 1.0f;
            #pragma unroll
            for (int mi = 0; mi < 2; ++mi) {
                #pragma unroll
                for (int nf = 0; nf < 8; ++nf) {
                    int col = nf * 16 + l16;
                    float bias = bqkv[n0 + col] * bscale;
                    #pragma unroll
                    for (int j = 0; j < 4; ++j) {
                        int rowl = w * 32 + mi * 16 + kh * 4 + j;
                        Bs[rowl][((col >> 3) ^ (rowl & 7)) * 8 + (col & 7)] = f2b(acc[mi][nf][j] + bias);
                    }
                }
            }
            __syncthreads();
            ushort* dst = (n0 == 0) ? qg : kg;
            for (int i = tid; i < 2048; i += 256) {
                int rl = i >> 4, c8 = i & 15;
                size_t rg = r0 + rl;
                if (rg < PTOT) {
                    uint4 v = *reinterpret_cast<const uint4*>(&Bs[rl][(c8 ^ (rl & 7)) * 8]);
                    *(reinterpret_cast<uint4*>(dst) + rg * 16 + c8) = v;
                }
            }
        } else {
            #pragma unroll
            for (int mi = 0; mi < 2; ++mi) {
                size_t rg0 = r0 + w * 32 + mi * 16 + kh * 4;
                if (rg0 < PTOT) {
                    int b = rg0 >= (size_t)NOUT;
                    size_t n = rg0 - (size_t)b * NOUT;
                    #pragma unroll
                    for (int nf = 0; nf < 8; ++nf) {
                        int col = nf * 16 + l16;
                        float bias = bqkv[256 + col];
                        uint2 st = { pk2(acc[mi][nf][0] + bias, acc[mi][nf][1] + bias),
                                     pk2(acc[mi][nf][2] + bias, acc[mi][nf][3] + bias) };
                        *reinterpret_cast<uint2*>(&vtg[((size_t)(b * 128 + col)) * NOUT + n]) = st;
                    }
                }
            }
        }
    }
}

// ---------------- kAttn: V read direct from global (K-only LDS = 28.8 KB -> 5 blocks/CU) -----
// V tail (keys >=360): per-lane address clamped to col 352 (in-bounds, finite) x P=0 -> exact 0.
__global__ __launch_bounds__(384) void kAttn(const ushort* __restrict__ qg, const ushort* __restrict__ kg,
                                             const ushort* __restrict__ vtg, ushort* __restrict__ og) {
    __shared__ ushort K_sm[360][40];   // 28.8 KB only
    int head = blockIdx.x, ring = blockIdx.y, b = blockIdx.z;
    int tid = threadIdx.x;
    size_t rowbase = (size_t)b * NOUT + (size_t)ring * 360;
    for (int i = tid; i < 1440; i += 384) {
        int r = i >> 2, c = (i & 3) * 8;
        uint4 val = *reinterpret_cast<const uint4*>(kg + (rowbase + r) * 128 + head * 32 + c);
        *reinterpret_cast<uint4*>(&K_sm[r][c]) = val;
    }
    __syncthreads();
    int wv = tid >> 6, lane = tid & 63;
    int lq = lane & 31, hi = lane >> 5;
    // per-lane V row pointer: d = lq, coalesced 64B-line groups across the wave
    const ushort* vrow = vtg + ((size_t)(b * 128 + head * 32 + lq)) * NOUT + (size_t)ring * 360;
    for (int qi = 0; qi < 2; ++qi) {
        int qt = wv + qi * 6;
        int qv = qt * 32 + lq;
        bool qok = qv < 360;
        uint4 qf1 = {0, 0, 0, 0}, qf2 = {0, 0, 0, 0};
        if (qok) {
            const ushort* qp = qg + (rowbase + qv) * 128 + head * 32;
            qf1 = *reinterpret_cast<const uint4*>(qp + hi * 8);
            qf2 = *reinterpret_cast<const uint4*>(qp + 16 + hi * 8);
        }
        s16x8 qa = __builtin_bit_cast(s16x8, qf1);
        s16x8 qb = __builtin_bit_cast(s16x8, qf2);
        f32x16v O;
        #pragma unroll
        for (int r2 = 0; r2 < 16; ++r2) O[r2] = 0.f;
        float ls0 = 0.f, ls1 = 0.f;
        #pragma unroll 1
        for (int kt = 0; kt < 12; ++kt) {
            // issue V loads early: latency hides under QK^T + softmax VALU
            int vc = kt * 32 + hi * 8;
            uint4 va_u = *reinterpret_cast<const uint4*>(vrow + min(vc, 352));
            uint4 vb_u = *reinterpret_cast<const uint4*>(vrow + min(vc + 16, 352));
            int krow = min(kt * 32 + lq, 359);
            s16x8 ka = *reinterpret_cast<const s16x8*>(&K_sm[krow][hi * 8]);
            s16x8 kb = *reinterpret_cast<const s16x8*>(&K_sm[krow][16 + hi * 8]);
            f32x16v S;
            #pragma unroll
            for (int r2 = 0; r2 < 16; ++r2) S[r2] = 0.f;
            S = __builtin_amdgcn_mfma_f32_32x32x16_bf16(ka, qa, S, 0, 0, 0);
            S = __builtin_amdgcn_mfma_f32_32x32x16_bf16(kb, qb, S, 0, 0, 0);
            if (kt == 11) {
                #pragma unroll
                for (int r2 = 4; r2 < 16; ++r2) S[r2] = -1e30f;
            }
            uint pw[8];
            #pragma unroll
            for (int pr = 0; pr < 8; ++pr) {
                float e0 = __builtin_amdgcn_exp2f(S[pr * 2]);
                float e1 = __builtin_amdgcn_exp2f(S[pr * 2 + 1]);
                pw[pr] = pk2(e0, e1);
                if (pr & 1) ls1 += e0 + e1; else ls0 += e0 + e1;
            }
            i32x2v r01 = __builtin_amdgcn_permlane32_swap((int)pw[0], (int)pw[2], false, false);
            i32x2v r11 = __builtin_amdgcn_permlane32_swap((int)pw[1], (int)pw[3], false, false);
            i32x2v r21 = __builtin_amdgcn_permlane32_swap((int)pw[4], (int)pw[6], false, false);
            i32x2v r31 = __builtin_amdgcn_permlane32_swap((int)pw[5], (int)pw[7], false, false);
            uint4 pf1u = {(uint)r01[0], (uint)r11[0], (uint)r01[1], (uint)r11[1]};
            uint4 pf2u = {(uint)r21[0], (uint)r31[0], (uint)r21[1], (uint)r31[1]};
            O = __builtin_amdgcn_mfma_f32_32x32x16_bf16(__builtin_bit_cast(s16x8, va_u),
                                                        __builtin_bit_cast(s16x8, pf1u), O, 0, 0, 0);
            O = __builtin_amdgcn_mfma_f32_32x32x16_bf16(__builtin_bit_cast(s16x8, vb_u),
                                                        __builtin_bit_cast(s16x8, pf2u), O, 0, 0, 0);
            __builtin_amdgcn_sched_barrier(0);   // pin iteration boundary: no cross-iter hoisting
        }
        float lsum = ls0 + ls1;
        i32x2v sw = __builtin_amdgcn_permlane32_swap(__float_as_int(lsum), __float_as_int(lsum), false, false);
        lsum = __int_as_float(sw[0]) + __int_as_float(sw[1]);
        float inv = 1.f / lsum;
        if (qok) {
            ushort* op = og + (rowbase + qv) * 128 + head * 32;
            #pragma unroll
            for (int g4 = 0; g4 < 4; ++g4) {
                int dbase = g4 * 8 + hi * 4;
                uint w0 = pk2(O[g4 * 4 + 0] * inv, O[g4 * 4 + 1] * inv);
                uint w1 = pk2(O[g4 * 4 + 2] * inv, O[g4 * 4 + 3] * inv);
                uint2 st = {w0, w1};
                *reinterpret_cast<uint2*>(op + dbase) = st;
            }
        }
    }
}

// ---------------- kFinal (MFMA): out[b][c][n] = (o @ wo)[n][c] + bo[c] + h[b][n][c] ----------
__global__ __launch_bounds__(256) void kFinal(const ushort* __restrict__ ob, const ushort* __restrict__ wot,
                                              const float* __restrict__ bo, const ushort* __restrict__ h16,
                                              float* __restrict__ out) {
    __shared__ ushort AB[2][128][128];
    int tid = threadIdx.x;
    size_t r0 = (size_t)blockIdx.x * 128;
    for (int i = tid; i < 2048; i += 256) {
        int rl = i >> 4, c8 = i & 15;
        size_t rg = r0 + rl;
        uint4 v = {0, 0, 0, 0};
        if (rg < PTOT) v = *reinterpret_cast<const uint4*>(ob + (rg << 7) + c8 * 8);
        *reinterpret_cast<uint4*>(&AB[0][rl][(c8 ^ (rl & 7)) * 8]) = v;
    }
    for (int i = tid; i < 2048; i += 256) {
        int rl = i >> 4, c8 = i & 15;
        uint4 v = *reinterpret_cast<const uint4*>(wot + ((size_t)rl << 7) + c8 * 8);
        *reinterpret_cast<uint4*>(&AB[1][rl][(c8 ^ (rl & 7)) * 8]) = v;
    }
    __syncthreads();
    int w = tid >> 6, lane = tid & 63;
    int l16 = lane & 15, kh = lane >> 4;
    int sa = l16 & 7;
    f32x4v acc[2][8];
    #pragma unroll
    for (int mi = 0; mi < 2; ++mi)
        #pragma unroll
        for (int nf = 0; nf < 8; ++nf) { acc[mi][nf][0] = 0; acc[mi][nf][1] = 0; acc[mi][nf][2] = 0; acc[mi][nf][3] = 0; }
    #pragma unroll
    for (int ks = 0; ks < 4; ++ks) {
        int c8 = ks * 4 + kh;
        s16x8 a0 = *reinterpret_cast<const s16x8*>(&AB[0][w * 32 + l16][(c8 ^ sa) * 8]);
        s16x8 a1 = *reinterpret_cast<const s16x8*>(&AB[0][w * 32 + 16 + l16][(c8 ^ sa) * 8]);
        #pragma unroll
        for (int nf = 0; nf < 8; ++nf) {
            int nn = nf * 16 + l16;
            s16x8 bf = *reinterpret_cast<const s16x8*>(&AB[1][nn][(c8 ^ (nn & 7)) * 8]);
            acc[0][nf] = __builtin_amdgcn_mfma_f32_16x16x32_bf16(a0, bf, acc[0][nf], 0, 0, 0);
            acc[1][nf] = __builtin_amdgcn_mfma_f32_16x16x32_bf16(a1, bf, acc[1][nf], 0, 0, 0);
        }
    }
    float* trf = reinterpret_cast<float*>(&AB[0][0][0]);
    const uint* h32 = reinterpret_cast<const uint*>(h16);
    int hw = w >> 1;
    for (int half = 0; half < 2; ++half) {
        __syncthreads();
        if (hw == half) {
            #pragma unroll
            for (int mi = 0; mi < 2; ++mi) {
                #pragma unroll
                for (int nf = 0; nf < 8; ++nf) {
                    int col = nf * 16 + l16;
                    float bv = bo[col];
                    #pragma unroll
                    for (int j = 0; j < 4; ++j) {
                        int relrow = (w & 1) * 32 + mi * 16 + kh * 4 + j;
                        trf[relrow * 129 + col] = acc[mi][nf][j] + bv;
                    }
                }
            }
        }
        __syncthreads();
        for (int i = tid; i < 4096; i += 256) {
            int rl = i >> 6, c2 = i & 63;
            size_t p = r0 + half * 64 + rl;
            if (p < PTOT) {
                uint hv = h32[p * 64 + c2];
                trf[rl * 129 + c2 * 2]     += b2f((ushort)(hv & 0xFFFF));
                trf[rl * 129 + c2 * 2 + 1] += b2f((ushort)(hv >> 16));
            }
        }
        __syncthreads();
        for (int i = tid; i < 8192; i += 256) {
            int c = i >> 6, rl = i & 63;
            size_t p = r0 + half * 64 + rl;
            if (p < PTOT) {
                int b = p >= (size_t)NOUT;
                size_t n = p - (size_t)b * NOUT;
                out[((size_t)(b * 128 + c)) * NOUT + n] = trf[rl * 129 + c];
            }
        }
    }
}

extern "C" void kernel_launch(void* const* d_in, const int* in_sizes, int n_in,
                              void* d_out, int out_size, void* d_ws, size_t ws_size,
                              hipStream_t stream) {
    const float* x    = (const float*)d_in[0];
    const float* skip = (const float*)d_in[1];
    const float* wd   = (const float*)d_in[2];
    const float* bd   = (const float*)d_in[3];
    const float* psi  = (const float*)d_in[4];
    const float* quad = (const float*)d_in[5];
    const float* g1   = (const float*)d_in[6];
    const float* b1   = (const float*)d_in[7];
    const float* g2   = (const float*)d_in[8];
    const float* b2   = (const float*)d_in[9];
    const float* wqkv = (const float*)d_in[10];
    const float* bqkv = (const float*)d_in[11];
    const float* wo   = (const float*)d_in[12];
    const float* bo   = (const float*)d_in[13];
    const int* row    = (const int*)d_in[14];
    const int* col    = (const int*)d_in[15];
    const int* ker    = (const int*)d_in[16];
    float* ws = (float*)d_ws;
    ushort* xw = (ushort*)ws;                // phase 1: bf16 [K][NIN][B][64]
    ushort* h16 = (ushort*)(ws + OFF_H);     // bf16 [PTOT][128]
    float* s1 = ws + OFF_S1;
    float* s2 = ws + OFF_S2;
    ushort* wtb = (ushort*)(ws + OFF_WT);
    int*   cnt = (int*)(ws + OFF_CNT);
    uint2* csr = (uint2*)(ws + OFF_CSR);
    ushort* qb  = (ushort*)(ws + OFF_Q);
    ushort* kb  = (ushort*)(ws + OFF_K);
    ushort* vtb = (ushort*)(ws + OFF_VT);
    ushort* wot = (ushort*)(ws + OFF_WOT);
    ushort* wqt = (ushort*)d_out;            // scratch: fully overwritten by kFinal
    float* out = (float*)d_out;

    hipMemsetAsync(s1, 0, 64 * sizeof(float), stream);      // s1 + s2
    hipMemsetAsync(cnt, 0, 65536 * sizeof(int), stream);

    kT<<<544, 256, 0, stream>>>(wd, wqkv, wo, wtb, wqt, wot);
    kFill<<<(NNZ_ + 255) / 256, 256, 0, stream>>>(row, col, ker, psi, cnt, csr);
    kA<<<dim3(128, B_), 256, 0, stream>>>(x, wtb, quad, xw);
    kGather<<<GGRID, 256, 0, stream>>>((const uint*)xw, cnt, csr, h16, bd, s1);
    kSkip<<<dim3(256, 2, B_), dim3(32, 8), 0, stream>>>(skip, h16, s2);
    kApply1<<<AGRID, 256, 0, stream>>>(h16, bd, g1, b1, s1, s2);
    kQKV<<<(int)((PTOT + 127) / 128), 256, 0, stream>>>(h16, wqt, bqkv, g2, b2, s2, qb, kb, vtb);
    kAttn<<<dim3(NH, HOUT, B_), 384, 0, stream>>>(qb, kb, vtb, qb /*o aliases q*/);
    kFinal<<<(int)((PTOT + 127) / 128), 256, 0, stream>>>(qb, wot, bo, h16, out);
}

// Round 16
// 425.460 us; speedup vs baseline: 1.0049x; 1.0049x over previous
//
#include <hip/hip_runtime.h>
#include <hip/hip_bf16.h>

#define B_ 2
#define CIN 128
#define HIN 91
#define WIN 180
#define NIN (HIN*WIN)         // 16380
#define COUT_ 64
#define HOUT 181
#define WOUT 360
#define NOUT (HOUT*WOUT)      // 65160
#define KK 9
#define NNZ_ (NOUT*8)         // 521280
#define CTOT 128
#define NH 4
#define HD 32
#define EPS_ 1e-5f
#define PTOT ((size_t)B_*NOUT)   // 130320
#define BCAP 40

// q pre-scale: 1/sqrt(32) * log2(e)  -> scores are in log2 domain; softmax uses exp2
#define QSCALE (0.17677669529663688f * 1.4426950408889634f)

typedef short s16x8 __attribute__((ext_vector_type(8)));
typedef float f32x4v __attribute__((ext_vector_type(4)));
typedef float f32x16v __attribute__((ext_vector_type(16)));
typedef int i32x2v __attribute__((ext_vector_type(2)));

// workspace layout (float offsets)
// h is bf16 [PTOT][128] (33.4 MB) in the OFF_H region.
#define OFF_Q  ((size_t)0)
#define OFF_K  ((size_t)8340480)
#define OFF_WOT ((size_t)16680960)                   // wot bf16 [128][128]
#define OFF_H  ((size_t)18869760)
#define OFF_S1 (OFF_H + (size_t)B_*NOUT*CTOT)        // 35550720
#define OFF_S2 (OFF_S1 + 32)
#define OFF_WT (OFF_S2 + 32)                         // wtb bf16 [K][64][128]
#define OFF_VT (OFF_WT + (size_t)KK*CIN*COUT_)       // vt bf16 spans [35624512, 43964992)
#define OFF_CNT OFF_VT                               // 65536 ints (aliases vt; dead before kQKV)
#define OFF_CSR (OFF_VT + 65536)                     // NOUT*BCAP uint2 (aliases vt; dead before kQKV)

__device__ inline ushort f2b(float x) { return __bfloat16_as_ushort(__float2bfloat16(x)); }
__device__ inline float b2f(ushort u) { return __bfloat162float(__ushort_as_bfloat16(u)); }
__device__ inline uint pk2(float lo, float hi) {
    return (uint)f2b(lo) | ((uint)f2b(hi) << 16);
}

// ---------------- kT: weight transposes (one-shot) -------------------------------------------
__global__ __launch_bounds__(256) void kT(const float* __restrict__ wd, const float* __restrict__ wqkv,
                                          const float* __restrict__ wo, ushort* __restrict__ wtb,
                                          ushort* __restrict__ wqt, ushort* __restrict__ wot) {
    int idx = blockIdx.x * 256 + threadIdx.x;
    if (idx < KK * CIN * COUT_) {
        int cin = idx & 127;
        int rest = idx >> 7;
        int cout = rest & 63;
        int k = rest >> 6;
        wtb[idx] = f2b(wd[((size_t)cout * CIN + cin) * KK + k]);
    } else if (idx < KK * CIN * COUT_ + 384 * 128) {
        int i2 = idx - KK * CIN * COUT_;
        int n = i2 >> 7, kk = i2 & 127;
        float v = wqkv[(size_t)kk * 384 + n];
        if (n < 128) v *= QSCALE;   // fold q-scale * log2(e)
        wqt[i2] = f2b(v);
    } else {
        int i3 = idx - (KK * CIN * COUT_ + 384 * 128);
        if (i3 < 128 * 128) {
            int n = i3 >> 7, kk = i3 & 127;
            wot[i3] = f2b(wo[(size_t)kk * 128 + n]);
        }
    }
}

// ---------------- kA v2 (MFMA): xw[k][n][b][cout] = bf16( (x*quad) @ wt[k] ) -----------------
__global__ __launch_bounds__(256) void kA(const float* __restrict__ x, const ushort* __restrict__ wtb,
                                          const float* __restrict__ quad, ushort* __restrict__ xw) {
    __shared__ ushort As[128][128];              // 32 KB, swizzled: A rows = n, cols = cin
    __shared__ __align__(16) char buf[16384];    // union: f32 strip tmp / Bs / bounce
    ushort (*Bs)[128] = reinterpret_cast<ushort(*)[128]>(buf);
    ushort (*Bo)[64]  = reinterpret_cast<ushort(*)[64]>(buf);
    float  (*tmp)[17] = reinterpret_cast<float(*)[17]>(buf);
    int tid = threadIdx.x;
    int n0 = blockIdx.x * 128;
    int b  = blockIdx.y;
    const float* xb = x + (size_t)b * CIN * NIN;
    for (int s = 0; s < 8; ++s) {
        int nbase = n0 + s * 16;
        for (int idx = tid; idx < 128 * 16; idx += 256) {
            int cin = idx >> 4, nn = idx & 15;
            int n = nbase + nn;
            tmp[cin][nn] = (n < NIN) ? xb[(size_t)cin * NIN + n] : 0.f;
        }
        __syncthreads();
        {
            int rl = tid >> 4, c8 = tid & 15;
            int n = nbase + rl;
            float qd = (n < NIN) ? quad[n / WIN] : 0.f;
            ushort w8[8];
            #pragma unroll
            for (int i = 0; i < 8; ++i) w8[i] = f2b(tmp[c8 * 8 + i][rl] * qd);
            int row = s * 16 + rl;
            *reinterpret_cast<uint4*>(&As[row][(c8 ^ (row & 7)) * 8]) = *reinterpret_cast<const uint4*>(w8);
        }
        __syncthreads();
    }
    int w = tid >> 6, lane = tid & 63;
    int l16 = lane & 15, kh = lane >> 4;
    int sa = l16 & 7;
    for (int k = 0; k < KK; ++k) {
        __syncthreads();
        for (int i = tid; i < 1024; i += 256) {
            int rl = i >> 4, c8 = i & 15;
            uint4 v = *reinterpret_cast<const uint4*>(wtb + (((size_t)k * 64 + rl) << 7) + c8 * 8);
            *reinterpret_cast<uint4*>(&Bs[rl][(c8 ^ (rl & 7)) * 8]) = v;
        }
        __syncthreads();
        f32x4v acc[2][4];
        #pragma unroll
        for (int mi = 0; mi < 2; ++mi)
            #pragma unroll
            for (int nf = 0; nf < 4; ++nf) { acc[mi][nf][0] = 0; acc[mi][nf][1] = 0; acc[mi][nf][2] = 0; acc[mi][nf][3] = 0; }
        #pragma unroll
        for (int ks = 0; ks < 4; ++ks) {
            int c8 = ks * 4 + kh;
            s16x8 a0 = *reinterpret_cast<const s16x8*>(&As[w * 32 + l16][(c8 ^ sa) * 8]);
            s16x8 a1 = *reinterpret_cast<const s16x8*>(&As[w * 32 + 16 + l16][(c8 ^ sa) * 8]);
            #pragma unroll
            for (int nf = 0; nf < 4; ++nf) {
                int nn = nf * 16 + l16;
                s16x8 bf = *reinterpret_cast<const s16x8*>(&Bs[nn][(c8 ^ (nn & 7)) * 8]);
                acc[0][nf] = __builtin_amdgcn_mfma_f32_16x16x32_bf16(a0, bf, acc[0][nf], 0, 0, 0);
                acc[1][nf] = __builtin_amdgcn_mfma_f32_16x16x32_bf16(a1, bf, acc[1][nf], 0, 0, 0);
            }
        }
        __syncthreads();
        #pragma unroll
        for (int mi = 0; mi < 2; ++mi) {
            #pragma unroll
            for (int nf = 0; nf < 4; ++nf) {
                int col = nf * 16 + l16;
                #pragma unroll
                for (int j = 0; j < 4; ++j) {
                    int rowl = w * 32 + mi * 16 + kh * 4 + j;
                    Bo[rowl][((col >> 3) ^ (rowl & 7)) * 8 + (col & 7)] = f2b(acc[mi][nf][j]);
                }
            }
        }
        __syncthreads();
        for (int i = tid; i < 1024; i += 256) {
            int rl = i >> 3, u = i & 7;
            int n = n0 + rl;
            if (n < NIN) {
                uint4 v = *reinterpret_cast<const uint4*>(&Bo[rl][(u ^ (rl & 7)) * 8]);
                *reinterpret_cast<uint4*>(xw + (((size_t)(k * NIN + n) * 2 + b) << 6) + u * 8) = v;
            }
        }
    }
}

// ---------------- kFill: bucket entries by output row ----------------------------------------
__global__ __launch_bounds__(256) void kFill(const int* __restrict__ row, const int* __restrict__ col,
                                             const int* __restrict__ ker, const float* __restrict__ psi,
                                             int* __restrict__ cnt, uint2* __restrict__ csr) {
    int e = blockIdx.x * 256 + threadIdx.x;
    if (e >= NNZ_) return;
    int r = row[e];
    int pos = atomicAdd(&cnt[r], 1);
    if (pos < BCAP) {
        uint2 pl;
        pl.x = (uint)col[e] | ((uint)ker[e] << 20);
        pl.y = __float_as_uint(psi[e]);
        csr[(size_t)r * BCAP + pos] = pl;
    }
}

// ---------------- kGather: h (bf16) ch0-63 = sum psi*xw ; fused GN1 stats --------------------
#define GGRID 2037
__global__ __launch_bounds__(256) void kGather(const uint* __restrict__ xw, const int* __restrict__ cnt,
                                               const uint2* __restrict__ csr, ushort* __restrict__ h16,
                                               const float* __restrict__ bd, float* __restrict__ s1) {
    int lane = threadIdx.x & 63;
    int wv = threadIdx.x >> 6;
    int b = lane >> 5;        // batch
    int c2 = lane & 31;       // cout pair index (couts 2*c2, 2*c2+1)
    float2 bdv = *reinterpret_cast<const float2*>(&bd[c2 * 2]);
    float sA = 0.f, qA = 0.f;
    uint* hw = reinterpret_cast<uint*>(h16);
    for (int r = blockIdx.x * 4 + wv; r < NOUT; r += GGRID * 4) {
        int n = min(cnt[r], BCAP);
        float a0 = 0.f, a1 = 0.f;
        const uint2* bucket = csr + (size_t)r * BCAP;
        for (int i = 0; i < n; ++i) {
            uint2 pl = bucket[i];
            int c = pl.x & 0xFFFFF;
            int kk = pl.x >> 20;
            float p = __uint_as_float(pl.y);
            uint v = xw[((size_t)kk * NIN + c) * 64 + lane];
            a0 = fmaf(p, b2f((ushort)(v & 0xFFFF)), a0);
            a1 = fmaf(p, b2f((ushort)(v >> 16)), a1);
        }
        hw[((size_t)b * NOUT + r) * 64 + c2] = pk2(a0, a1);
        float y0 = a0 + bdv.x, y1 = a1 + bdv.y;
        sA += y0 + y1; qA += y0 * y0 + y1 * y1;
    }
    #pragma unroll
    for (int o = 1; o <= 2; o <<= 1) { sA += __shfl_xor(sA, o); qA += __shfl_xor(qA, o); }
    __shared__ float red[4][2][8][2];
    if ((lane & 3) == 0) {
        red[wv][b][c2 >> 2][0] = sA;
        red[wv][b][c2 >> 2][1] = qA;
    }
    __syncthreads();
    if (threadIdx.x < 32) {
        int bb = threadIdx.x >> 4, g = (threadIdx.x >> 1) & 7, isq = threadIdx.x & 1;
        float v = red[0][bb][g][isq] + red[1][bb][g][isq] + red[2][bb][g][isq] + red[3][bb][g][isq];
        atomicAdd(&s1[(bb * 8 + g) * 2 + isq], v);
    }
}

// ---------------- kSkip: transpose skip into h (bf16) ch64..127; fused GN2 stats 4..7 --------
__global__ void kSkip(const float* __restrict__ skip, ushort* __restrict__ h16, float* __restrict__ s2) {
    __shared__ float tile[32][33];
    __shared__ float acc4[4];
    int c0 = blockIdx.y * 32, b = blockIdx.z;
    int tx = threadIdx.x, ty = threadIdx.y;
    int tid = ty * 32 + tx;
    if (tid < 4) acc4[tid] = 0.f;
    float sA[2] = {0.f, 0.f}, qA[2] = {0.f, 0.f};
    uint* hw = reinterpret_cast<uint*>(h16);
    for (int n0 = blockIdx.x * 32; n0 < NOUT; n0 += 256 * 32) {
        #pragma unroll
        for (int j = 0; j < 4; ++j) {
            int c = c0 + ty + j * 8, n = n0 + tx;
            if (n < NOUT) {
                float v = skip[((size_t)b * 64 + c) * NOUT + n];
                tile[ty + j * 8][tx] = v;
                int gi = (ty + 8 * j) >> 4;
                sA[gi] += v; qA[gi] += v * v;
            }
        }
        __syncthreads();
        for (int idx = tid; idx < 512; idx += 256) {   // 32 n x 16 channel-pairs
            int nn = idx >> 4, cp = idx & 15;
            int n = n0 + nn;
            if (n < NOUT) {
                uint st = pk2(tile[cp * 2][nn], tile[cp * 2 + 1][nn]);
                hw[((size_t)b * NOUT + n) * 64 + 32 + (c0 >> 1) + cp] = st;   // ch 64+c0+2cp
            }
        }
        __syncthreads();
    }
    atomicAdd(&acc4[0], sA[0]); atomicAdd(&acc4[1], qA[0]);
    atomicAdd(&acc4[2], sA[1]); atomicAdd(&acc4[3], qA[1]);
    __syncthreads();
    if (tid < 4) {
        int gi = tid >> 1, isq = tid & 1;
        int g = 4 + (c0 >> 4) + gi;
        atomicAdd(&s2[(b * 8 + g) * 2 + isq], acc4[tid]);
    }
}

// ---------------- kApply1: GN1 + GELU in place (bf16 h); fused GN2 stats groups 0..3 ---------
#define AGRID 2048
__global__ __launch_bounds__(256) void kApply1(ushort* __restrict__ h16, const float* __restrict__ bd,
                                               const float* __restrict__ g1, const float* __restrict__ b1,
                                               const float* __restrict__ s1, float* __restrict__ s2) {
    int tid = threadIdx.x;
    int c8g = tid & 7;
    int lane = tid & 63, wv = tid >> 6;
    const float invc = 1.0f / (8.0f * NOUT);
    float mu0 = s1[c8g * 2] * invc;
    float r0 = rsqrtf(s1[c8g * 2 + 1] * invc - mu0 * mu0 + EPS_);
    float mu1 = s1[(8 + c8g) * 2] * invc;
    float r1 = rsqrtf(s1[(8 + c8g) * 2 + 1] * invc - mu1 * mu1 + EPS_);
    float bdv[8], g1v[8], b1v[8];
    #pragma unroll
    for (int j = 0; j < 8; ++j) {
        int c = c8g * 8 + j;
        bdv[j] = bd[c]; g1v[j] = g1[c]; b1v[j] = b1[c];
    }
    float sA[2] = {0.f, 0.f}, qA[2] = {0.f, 0.f};
    const size_t total = (size_t)B_ * NOUT * 8;
    uint4* hb = reinterpret_cast<uint4*>(h16);
    for (size_t idx = (size_t)blockIdx.x * 256 + tid; idx < total; idx += (size_t)AGRID * 256) {
        size_t pn = idx >> 3;
        int b = pn >= (size_t)NOUT;
        float mu = b ? mu1 : mu0, rstd = b ? r1 : r0;
        uint4* p = hb + pn * 16 + c8g;
        uint4 hv = *p;
        const ushort* hs = reinterpret_cast<const ushort*>(&hv);
        float ls = 0.f, lq = 0.f;
        uint outw[4];
        #pragma unroll
        for (int jp = 0; jp < 4; ++jp) {
            float a0 = b2f(hs[jp * 2]) + bdv[jp * 2];
            float a1 = b2f(hs[jp * 2 + 1]) + bdv[jp * 2 + 1];
            float t0 = (a0 - mu) * rstd * g1v[jp * 2] + b1v[jp * 2];
            float t1 = (a1 - mu) * rstd * g1v[jp * 2 + 1] + b1v[jp * 2 + 1];
            float ge0 = t0 * 0.5f * (1.0f + erff(t0 * 0.70710678118654752f));
            float ge1 = t1 * 0.5f * (1.0f + erff(t1 * 0.70710678118654752f));
            ls += ge0 + ge1; lq += ge0 * ge0 + ge1 * ge1;
            outw[jp] = pk2(ge0, ge1);
        }
        sA[b] += ls; qA[b] += lq;
        uint4 st = {outw[0], outw[1], outw[2], outw[3]};
        *p = st;
    }
    #pragma unroll
    for (int o = 8; o <= 32; o <<= 1) {
        sA[0] += __shfl_xor(sA[0], o); qA[0] += __shfl_xor(qA[0], o);
        sA[1] += __shfl_xor(sA[1], o); qA[1] += __shfl_xor(qA[1], o);
    }
    sA[0] += __shfl_xor(sA[0], 1); qA[0] += __shfl_xor(qA[0], 1);
    sA[1] += __shfl_xor(sA[1], 1); qA[1] += __shfl_xor(qA[1], 1);
    __shared__ float red[4][4][4];
    if (lane < 8 && !(lane & 1)) {
        int g = lane >> 1;
        red[wv][g][0] = sA[0]; red[wv][g][1] = qA[0];
        red[wv][g][2] = sA[1]; red[wv][g][3] = qA[1];
    }
    __syncthreads();
    if (tid < 16) {
        int g = tid >> 2, q = tid & 3;
        float v = red[0][g][q] + red[1][g][q] + red[2][g][q] + red[3][g][q];
        int b = q >> 1, isq = q & 1;
        atomicAdd(&s2[(b * 8 + g) * 2 + isq], v);
    }
}

// ---------------- kQKV: one h pass (bf16), swizzled LDS, 3 output chunks ---------------------
__global__ __launch_bounds__(256) void kQKV(const ushort* __restrict__ h16, const ushort* __restrict__ wqt,
                                            const float* __restrict__ bqkv, const float* __restrict__ g2,
                                            const float* __restrict__ b2, const float* __restrict__ s2,
                                            ushort* __restrict__ qg, ushort* __restrict__ kg,
                                            ushort* __restrict__ vtg) {
    __shared__ ushort As[128][128];
    __shared__ ushort Bs[128][128];
    __shared__ float muT[16], rsT[16], g2T[128], b2T[128];
    int tid = threadIdx.x;
    size_t r0 = (size_t)blockIdx.x * 128;
    const float invc2 = 1.0f / (16.0f * NOUT);
    if (tid < 16) {
        float mu = s2[tid * 2] * invc2;
        float ex2 = s2[tid * 2 + 1] * invc2;
        muT[tid] = mu;
        rsT[tid] = rsqrtf(ex2 - mu * mu + EPS_);
    }
    if (tid < 128) { g2T[tid] = g2[tid]; b2T[tid] = b2[tid]; }
    __syncthreads();
    const uint4* hb = reinterpret_cast<const uint4*>(h16);
    for (int i = tid; i < 2048; i += 256) {
        int rl = i >> 4, c8 = i & 15;
        size_t rg = r0 + rl;
        uint4 wv = {0, 0, 0, 0};
        if (rg < PTOT) {
            int c = c8 * 8;
            int g = ((rg >= (size_t)NOUT) ? 8 : 0) + (c >> 4);
            float mu = muT[g], rs = rsT[g];
            uint4 hv = hb[rg * 16 + c8];
            const ushort* hs = reinterpret_cast<const ushort*>(&hv);
            float t[8];
            #pragma unroll
            for (int j = 0; j < 8; ++j)
                t[j] = (b2f(hs[j]) - mu) * rs * g2T[c + j] + b2T[c + j];
            wv.x = pk2(t[0], t[1]); wv.y = pk2(t[2], t[3]);
            wv.z = pk2(t[4], t[5]); wv.w = pk2(t[6], t[7]);
        }
        *reinterpret_cast<uint4*>(&As[rl][(c8 ^ (rl & 7)) * 8]) = wv;
    }
    int w = tid >> 6, lane = tid & 63;
    int l16 = lane & 15, kh = lane >> 4;
    int sa = l16 & 7;
    for (int n0 = 0; n0 < 384; n0 += 128) {
        __syncthreads();
        for (int i = tid; i < 2048; i += 256) {
            int rl = i >> 4, c8 = i & 15;
            uint4 v = *reinterpret_cast<const uint4*>(wqt + ((size_t)(n0 + rl) << 7) + c8 * 8);
            *reinterpret_cast<uint4*>(&Bs[rl][(c8 ^ (rl & 7)) * 8]) = v;
        }
        __syncthreads();
        f32x4v acc[2][8];
        #pragma unroll
        for (int mi = 0; mi < 2; ++mi)
            #pragma unroll
            for (int nf = 0; nf < 8; ++nf) { acc[mi][nf][0] = 0; acc[mi][nf][1] = 0; acc[mi][nf][2] = 0; acc[mi][nf][3] = 0; }
        #pragma unroll
        for (int ks = 0; ks < 4; ++ks) {
            int c8 = ks * 4 + kh;
            s16x8 a0 = *reinterpret_cast<const s16x8*>(&As[w * 32 + l16][(c8 ^ sa) * 8]);
            s16x8 a1 = *reinterpret_cast<const s16x8*>(&As[w * 32 + 16 + l16][(c8 ^ sa) * 8]);
            #pragma unroll
            for (int nf = 0; nf < 8; ++nf) {
                int nn = nf * 16 + l16;
                s16x8 bf = *reinterpret_cast<const s16x8*>(&Bs[nn][(c8 ^ (nn & 7)) * 8]);
                acc[0][nf] = __builtin_amdgcn_mfma_f32_16x16x32_bf16(a0, bf, acc[0][nf], 0, 0, 0);
                acc[1][nf] = __builtin_amdgcn_mfma_f32_16x16x32_bf16(a1, bf, acc[1][nf], 0, 0, 0);
            }
        }
        if (n0 < 256) {
            __syncthreads();
            const float bscale = (n0 == 0) ? QSCALE : 1.0f;
            #pragma unroll
            for (int mi = 0; mi < 2; ++mi) {
                #pragma unroll
                for (int nf = 0; nf < 8; ++nf) {
                    int col = nf * 16 + l16;
                    float bias = bqkv[n0 + col] * bscale;
                    #pragma unroll
                    for (int j = 0; j < 4; ++j) {
                        int rowl = w * 32 + mi * 16 + kh * 4 + j;
                        Bs[rowl][((col >> 3) ^ (rowl & 7)) * 8 + (col & 7)] = f2b(acc[mi][nf][j] + bias);
                    }
                }
            }
            __syncthreads();
            ushort* dst = (n0 == 0) ? qg : kg;
            for (int i = tid; i < 2048; i += 256) {
                int rl = i >> 4, c8 = i & 15;
                size_t rg = r0 + rl;
                if (rg < PTOT) {
                    uint4 v = *reinterpret_cast<const uint4*>(&Bs[rl][(c8 ^ (rl & 7)) * 8]);
                    *(reinterpret_cast<uint4*>(dst) + rg * 16 + c8) = v;
                }
            }
        } else {
            #pragma unroll
            for (int mi = 0; mi < 2; ++mi) {
                size_t rg0 = r0 + w * 32 + mi * 16 + kh * 4;
                if (rg0 < PTOT) {
                    int b = rg0 >= (size_t)NOUT;
                    size_t n = rg0 - (size_t)b * NOUT;
                    #pragma unroll
                    for (int nf = 0; nf < 8; ++nf) {
                        int col = nf * 16 + l16;
                        float bias = bqkv[256 + col];
                        uint2 st = { pk2(acc[mi][nf][0] + bias, acc[mi][nf][1] + bias),
                                     pk2(acc[mi][nf][2] + bias, acc[mi][nf][3] + bias) };
                        *reinterpret_cast<uint2*>(&vtg[((size_t)(b * 128 + col)) * NOUT + n]) = st;
                    }
                }
            }
        }
    }
}

// ---------------- kAttn: V in LDS, kt-outer loop feeds BOTH q-tiles per K/V fragment ---------
__global__ __launch_bounds__(384) void kAttn(const ushort* __restrict__ qg, const ushort* __restrict__ kg,
                                             const ushort* __restrict__ vtg, ushort* __restrict__ og) {
    __shared__ ushort K_sm[360][40];   // 28.8 KB
    __shared__ ushort V_sm[32][392];   // 25.1 KB; total 53.9 KB -> 2 blocks/CU (LDS-capped)
    int head = blockIdx.x, ring = blockIdx.y, b = blockIdx.z;
    int tid = threadIdx.x;
    size_t rowbase = (size_t)b * NOUT + (size_t)ring * 360;
    for (int i = tid; i < 1440; i += 384) {
        int r = i >> 2, c = (i & 3) * 8;
        uint4 val = *reinterpret_cast<const uint4*>(kg + (rowbase + r) * 128 + head * 32 + c);
        *reinterpret_cast<uint4*>(&K_sm[r][c]) = val;
    }
    {
        int d = tid / 12, j = tid % 12;
        const ushort* vp = vtg + ((size_t)(b * 128 + head * 32 + d)) * NOUT + (size_t)ring * 360;
        for (int c8 = j; c8 < 49; c8 += 12) {
            uint4 val = {0, 0, 0, 0};
            if (c8 < 45) val = *reinterpret_cast<const uint4*>(vp + c8 * 8);
            *reinterpret_cast<uint4*>(&V_sm[d][c8 * 8]) = val;   // tail cols zeroed
        }
    }
    __syncthreads();
    int wv = tid >> 6, lane = tid & 63;
    int lq = lane & 31, hi = lane >> 5;
    // load q fragments for both q-tiles upfront
    s16x8 qa[2], qb[2];
    bool qok[2];
    int qvv[2];
    #pragma unroll
    for (int qi = 0; qi < 2; ++qi) {
        int qt = wv + qi * 6;
        qvv[qi] = qt * 32 + lq;
        qok[qi] = qvv[qi] < 360;
        uint4 qf1 = {0, 0, 0, 0}, qf2 = {0, 0, 0, 0};
        if (qok[qi]) {
            const ushort* qp = qg + (rowbase + qvv[qi]) * 128 + head * 32;
            qf1 = *reinterpret_cast<const uint4*>(qp + hi * 8);
            qf2 = *reinterpret_cast<const uint4*>(qp + 16 + hi * 8);
        }
        qa[qi] = __builtin_bit_cast(s16x8, qf1);
        qb[qi] = __builtin_bit_cast(s16x8, qf2);
    }
    f32x16v O[2];
    #pragma unroll
    for (int qi = 0; qi < 2; ++qi)
        #pragma unroll
        for (int r2 = 0; r2 < 16; ++r2) O[qi][r2] = 0.f;
    float ls0[2] = {0.f, 0.f}, ls1[2] = {0.f, 0.f};
    #pragma unroll 1
    for (int kt = 0; kt < 12; ++kt) {
        int krow = min(kt * 32 + lq, 359);
        s16x8 ka = *reinterpret_cast<const s16x8*>(&K_sm[krow][hi * 8]);
        s16x8 kb = *reinterpret_cast<const s16x8*>(&K_sm[krow][16 + hi * 8]);
        s16x8 va = *reinterpret_cast<const s16x8*>(&V_sm[lq][kt * 32 + hi * 8]);
        s16x8 vb = *reinterpret_cast<const s16x8*>(&V_sm[lq][kt * 32 + 16 + hi * 8]);
        #pragma unroll
        for (int qi = 0; qi < 2; ++qi) {   // fully unrolled: static O[qi] indexing
            f32x16v S;
            #pragma unroll
            for (int r2 = 0; r2 < 16; ++r2) S[r2] = 0.f;
            S = __builtin_amdgcn_mfma_f32_32x32x16_bf16(ka, qa[qi], S, 0, 0, 0);
            S = __builtin_amdgcn_mfma_f32_32x32x16_bf16(kb, qb[qi], S, 0, 0, 0);
            if (kt == 11) {   // keys >=360 -> exp2(-1e30) = 0
                #pragma unroll
                for (int r2 = 4; r2 < 16; ++r2) S[r2] = -1e30f;
            }
            uint pw[8];
            #pragma unroll
            for (int pr = 0; pr < 8; ++pr) {
                float e0 = __builtin_amdgcn_exp2f(S[pr * 2]);
                float e1 = __builtin_amdgcn_exp2f(S[pr * 2 + 1]);
                pw[pr] = pk2(e0, e1);
                if (pr & 1) ls1[qi] += e0 + e1; else ls0[qi] += e0 + e1;
            }
            i32x2v r01 = __builtin_amdgcn_permlane32_swap((int)pw[0], (int)pw[2], false, false);
            i32x2v r11 = __builtin_amdgcn_permlane32_swap((int)pw[1], (int)pw[3], false, false);
            i32x2v r21 = __builtin_amdgcn_permlane32_swap((int)pw[4], (int)pw[6], false, false);
            i32x2v r31 = __builtin_amdgcn_permlane32_swap((int)pw[5], (int)pw[7], false, false);
            uint4 pf1u = {(uint)r01[0], (uint)r11[0], (uint)r01[1], (uint)r11[1]};
            uint4 pf2u = {(uint)r21[0], (uint)r31[0], (uint)r21[1], (uint)r31[1]};
            O[qi] = __builtin_amdgcn_mfma_f32_32x32x16_bf16(va, __builtin_bit_cast(s16x8, pf1u), O[qi], 0, 0, 0);
            O[qi] = __builtin_amdgcn_mfma_f32_32x32x16_bf16(vb, __builtin_bit_cast(s16x8, pf2u), O[qi], 0, 0, 0);
        }
        __builtin_amdgcn_sched_barrier(0);   // pin iteration boundary: no cross-iter hoisting
    }
    #pragma unroll
    for (int qi = 0; qi < 2; ++qi) {
        float lsum = ls0[qi] + ls1[qi];
        i32x2v sw = __builtin_amdgcn_permlane32_swap(__float_as_int(lsum), __float_as_int(lsum), false, false);
        lsum = __int_as_float(sw[0]) + __int_as_float(sw[1]);
        float inv = 1.f / lsum;
        if (qok[qi]) {
            ushort* op = og + (rowbase + qvv[qi]) * 128 + head * 32;
            #pragma unroll
            for (int g4 = 0; g4 < 4; ++g4) {
                int dbase = g4 * 8 + hi * 4;
                uint w0 = pk2(O[qi][g4 * 4 + 0] * inv, O[qi][g4 * 4 + 1] * inv);
                uint w1 = pk2(O[qi][g4 * 4 + 2] * inv, O[qi][g4 * 4 + 3] * inv);
                uint2 st = {w0, w1};
                *reinterpret_cast<uint2*>(op + dbase) = st;
            }
        }
    }
}

// ---------------- kFinal (MFMA): out[b][c][n] = (o @ wo)[n][c] + bo[c] + h[b][n][c] ----------
__global__ __launch_bounds__(256) void kFinal(const ushort* __restrict__ ob, const ushort* __restrict__ wot,
                                              const float* __restrict__ bo, const ushort* __restrict__ h16,
                                              float* __restrict__ out) {
    __shared__ ushort AB[2][128][128];
    int tid = threadIdx.x;
    size_t r0 = (size_t)blockIdx.x * 128;
    for (int i = tid; i < 2048; i += 256) {
        int rl = i >> 4, c8 = i & 15;
        size_t rg = r0 + rl;
        uint4 v = {0, 0, 0, 0};
        if (rg < PTOT) v = *reinterpret_cast<const uint4*>(ob + (rg << 7) + c8 * 8);
        *reinterpret_cast<uint4*>(&AB[0][rl][(c8 ^ (rl & 7)) * 8]) = v;
    }
    for (int i = tid; i < 2048; i += 256) {
        int rl = i >> 4, c8 = i & 15;
        uint4 v = *reinterpret_cast<const uint4*>(wot + ((size_t)rl << 7) + c8 * 8);
        *reinterpret_cast<uint4*>(&AB[1][rl][(c8 ^ (rl & 7)) * 8]) = v;
    }
    __syncthreads();
    int w = tid >> 6, lane = tid & 63;
    int l16 = lane & 15, kh = lane >> 4;
    int sa = l16 & 7;
    f32x4v acc[2][8];
    #pragma unroll
    for (int mi = 0; mi < 2; ++mi)
        #pragma unroll
        for (int nf = 0; nf < 8; ++nf) { acc[mi][nf][0] = 0; acc[mi][nf][1] = 0; acc[mi][nf][2] = 0; acc[mi][nf][3] = 0; }
    #pragma unroll
    for (int ks = 0; ks < 4; ++ks) {
        int c8 = ks * 4 + kh;
        s16x8 a0 = *reinterpret_cast<const s16x8*>(&AB[0][w * 32 + l16][(c8 ^ sa) * 8]);
        s16x8 a1 = *reinterpret_cast<const s16x8*>(&AB[0][w * 32 + 16 + l16][(c8 ^ sa) * 8]);
        #pragma unroll
        for (int nf = 0; nf < 8; ++nf) {
            int nn = nf * 16 + l16;
            s16x8 bf = *reinterpret_cast<const s16x8*>(&AB[1][nn][(c8 ^ (nn & 7)) * 8]);
            acc[0][nf] = __builtin_amdgcn_mfma_f32_16x16x32_bf16(a0, bf, acc[0][nf], 0, 0, 0);
            acc[1][nf] = __builtin_amdgcn_mfma_f32_16x16x32_bf16(a1, bf, acc[1][nf], 0, 0, 0);
        }
    }
    float* trf = reinterpret_cast<float*>(&AB[0][0][0]);
    const uint* h32 = reinterpret_cast<const uint*>(h16);
    int hw = w >> 1;
    for (int half = 0; half < 2; ++half) {
        __syncthreads();
        if (hw == half) {
            #pragma unroll
            for (int mi = 0; mi < 2; ++mi) {
                #pragma unroll
                for (int nf = 0; nf < 8; ++nf) {
                    int col = nf * 16 + l16;
                    float bv = bo[col];
                    #pragma unroll
                    for (int j = 0; j < 4; ++j) {
                        int relrow = (w & 1) * 32 + mi * 16 + kh * 4 + j;
                        trf[relrow * 129 + col] = acc[mi][nf][j] + bv;
                    }
                }
            }
        }
        __syncthreads();
        for (int i = tid; i < 4096; i += 256) {
            int rl = i >> 6, c2 = i & 63;
            size_t p = r0 + half * 64 + rl;
            if (p < PTOT) {
                uint hv = h32[p * 64 + c2];
                trf[rl * 129 + c2 * 2]     += b2f((ushort)(hv & 0xFFFF));
                trf[rl * 129 + c2 * 2 + 1] += b2f((ushort)(hv >> 16));
            }
        }
        __syncthreads();
        for (int i = tid; i < 8192; i += 256) {
            int c = i >> 6, rl = i & 63;
            size_t p = r0 + half * 64 + rl;
            if (p < PTOT) {
                int b = p >= (size_t)NOUT;
                size_t n = p - (size_t)b * NOUT;
                out[((size_t)(b * 128 + c)) * NOUT + n] = trf[rl * 129 + c];
            }
        }
    }
}

extern "C" void kernel_launch(void* const* d_in, const int* in_sizes, int n_in,
                              void* d_out, int out_size, void* d_ws, size_t ws_size,
                              hipStream_t stream) {
    const float* x    = (const float*)d_in[0];
    const float* skip = (const float*)d_in[1];
    const float* wd   = (const float*)d_in[2];
    const float* bd   = (const float*)d_in[3];
    const float* psi  = (const float*)d_in[4];
    const float* quad = (const float*)d_in[5];
    const float* g1   = (const float*)d_in[6];
    const float* b1   = (const float*)d_in[7];
    const float* g2   = (const float*)d_in[8];
    const float* b2   = (const float*)d_in[9];
    const float* wqkv = (const float*)d_in[10];
    const float* bqkv = (const float*)d_in[11];
    const float* wo   = (const float*)d_in[12];
    const float* bo   = (const float*)d_in[13];
    const int* row    = (const int*)d_in[14];
    const int* col    = (const int*)d_in[15];
    const int* ker    = (const int*)d_in[16];
    float* ws = (float*)d_ws;
    ushort* xw = (ushort*)ws;                // phase 1: bf16 [K][NIN][B][64]
    ushort* h16 = (ushort*)(ws + OFF_H);     // bf16 [PTOT][128]
    float* s1 = ws + OFF_S1;
    float* s2 = ws + OFF_S2;
    ushort* wtb = (ushort*)(ws + OFF_WT);
    int*   cnt = (int*)(ws + OFF_CNT);
    uint2* csr = (uint2*)(ws + OFF_CSR);
    ushort* qb  = (ushort*)(ws + OFF_Q);
    ushort* kb  = (ushort*)(ws + OFF_K);
    ushort* vtb = (ushort*)(ws + OFF_VT);
    ushort* wot = (ushort*)(ws + OFF_WOT);
    ushort* wqt = (ushort*)d_out;            // scratch: fully overwritten by kFinal
    float* out = (float*)d_out;

    hipMemsetAsync(s1, 0, 64 * sizeof(float), stream);      // s1 + s2
    hipMemsetAsync(cnt, 0, 65536 * sizeof(int), stream);

    kT<<<544, 256, 0, stream>>>(wd, wqkv, wo, wtb, wqt, wot);
    kFill<<<(NNZ_ + 255) / 256, 256, 0, stream>>>(row, col, ker, psi, cnt, csr);
    kA<<<dim3(128, B_), 256, 0, stream>>>(x, wtb, quad, xw);
    kGather<<<GGRID, 256, 0, stream>>>((const uint*)xw, cnt, csr, h16, bd, s1);
    kSkip<<<dim3(256, 2, B_), dim3(32, 8), 0, stream>>>(skip, h16, s2);
    kApply1<<<AGRID, 256, 0, stream>>>(h16, bd, g1, b1, s1, s2);
    kQKV<<<(int)((PTOT + 127) / 128), 256, 0, stream>>>(h16, wqt, bqkv, g2, b2, s2, qb, kb, vtb);
    kAttn<<<dim3(NH, HOUT, B_), 384, 0, stream>>>(qb, kb, vtb, qb /*o aliases q*/);
    kFinal<<<(int)((PTOT + 127) / 128), 256, 0, stream>>>(qb, wot, bo, h16, out);
}

// Round 17
// 383.162 us; speedup vs baseline: 1.1158x; 1.1104x over previous
//
#include <hip/hip_runtime.h>
#include <hip/hip_bf16.h>

#define B_ 2
#define CIN 128
#define HIN 91
#define WIN 180
#define NIN (HIN*WIN)         // 16380
#define COUT_ 64
#define HOUT 181
#define WOUT 360
#define NOUT (HOUT*WOUT)      // 65160
#define KK 9
#define NNZ_ (NOUT*8)         // 521280
#define CTOT 128
#define NH 4
#define HD 32
#define EPS_ 1e-5f
#define PTOT ((size_t)B_*NOUT)   // 130320
#define BCAP 40

// q pre-scale: 1/sqrt(32) * log2(e)  -> scores are in log2 domain; softmax uses exp2
#define QSCALE (0.17677669529663688f * 1.4426950408889634f)

typedef short s16x8 __attribute__((ext_vector_type(8)));
typedef float f32x4v __attribute__((ext_vector_type(4)));
typedef float f32x16v __attribute__((ext_vector_type(16)));
typedef int i32x2v __attribute__((ext_vector_type(2)));

// workspace layout (float offsets); h is bf16 [PTOT][128]
#define OFF_Q  ((size_t)0)
#define OFF_K  ((size_t)8340480)
#define OFF_WOT ((size_t)16680960)                   // wot bf16 [128][128]
#define OFF_H  ((size_t)18869760)
#define OFF_S1 (OFF_H + (size_t)B_*NOUT*CTOT)        // 35550720
#define OFF_S2 (OFF_S1 + 32)
#define OFF_WT (OFF_S2 + 32)                         // wtb bf16 [K][64][128]
#define OFF_VT (OFF_WT + (size_t)KK*CIN*COUT_)       // vt bf16
#define OFF_CNT OFF_VT                               // 65536 ints (aliases vt)
#define OFF_CSR (OFF_VT + 65536)                     // NOUT*BCAP uint2 (aliases vt)

__device__ inline ushort f2b(float x) { return __bfloat16_as_ushort(__float2bfloat16(x)); }
__device__ inline float b2f(ushort u) { return __bfloat162float(__ushort_as_bfloat16(u)); }
__device__ inline uint pk2(float lo, float hi) {
    return (uint)f2b(lo) | ((uint)f2b(hi) << 16);
}

// ---------------- kT: weight transposes (one-shot) -------------------------------------------
__global__ __launch_bounds__(256) void kT(const float* __restrict__ wd, const float* __restrict__ wqkv,
                                          const float* __restrict__ wo, ushort* __restrict__ wtb,
                                          ushort* __restrict__ wqt, ushort* __restrict__ wot) {
    int idx = blockIdx.x * 256 + threadIdx.x;
    if (idx < KK * CIN * COUT_) {
        int cin = idx & 127;
        int rest = idx >> 7;
        int cout = rest & 63;
        int k = rest >> 6;
        wtb[idx] = f2b(wd[((size_t)cout * CIN + cin) * KK + k]);
    } else if (idx < KK * CIN * COUT_ + 384 * 128) {
        int i2 = idx - KK * CIN * COUT_;
        int n = i2 >> 7, kk = i2 & 127;
        float v = wqkv[(size_t)kk * 384 + n];
        if (n < 128) v *= QSCALE;   // fold q-scale * log2(e)
        wqt[i2] = f2b(v);
    } else {
        int i3 = idx - (KK * CIN * COUT_ + 384 * 128);
        if (i3 < 128 * 128) {
            int n = i3 >> 7, kk = i3 & 127;
            wot[i3] = f2b(wo[(size_t)kk * 128 + n]);
        }
    }
}

// ---------------- kAF: fused kA (MFMA, blocks 0..255) + kFill (blocks 256..2292) -------------
#define KA_BLOCKS 256
__global__ __launch_bounds__(256) void kAF(const float* __restrict__ x, const ushort* __restrict__ wtb,
                                           const float* __restrict__ quad, ushort* __restrict__ xw,
                                           const int* __restrict__ row, const int* __restrict__ col,
                                           const int* __restrict__ ker, const float* __restrict__ psi,
                                           int* __restrict__ cnt, uint2* __restrict__ csr) {
    __shared__ ushort As[128][128];              // 32 KB (kA path only)
    __shared__ __align__(16) char buf[16384];
    int tid = threadIdx.x;
    if (blockIdx.x >= KA_BLOCKS) {
        // ---- kFill path ----
        int e = (blockIdx.x - KA_BLOCKS) * 256 + tid;
        if (e < NNZ_) {
            int r = row[e];
            int pos = atomicAdd(&cnt[r], 1);
            if (pos < BCAP) {
                uint2 pl;
                pl.x = (uint)col[e] | ((uint)ker[e] << 20);
                pl.y = __float_as_uint(psi[e]);
                csr[(size_t)r * BCAP + pos] = pl;
            }
        }
        return;
    }
    // ---- kA path ----
    ushort (*Bs)[128] = reinterpret_cast<ushort(*)[128]>(buf);
    ushort (*Bo)[64]  = reinterpret_cast<ushort(*)[64]>(buf);
    float  (*tmp)[17] = reinterpret_cast<float(*)[17]>(buf);
    int n0 = (blockIdx.x & 127) * 128;
    int b  = blockIdx.x >> 7;
    const float* xb = x + (size_t)b * CIN * NIN;
    for (int s = 0; s < 8; ++s) {
        int nbase = n0 + s * 16;
        for (int idx = tid; idx < 128 * 16; idx += 256) {
            int cin = idx >> 4, nn = idx & 15;
            int n = nbase + nn;
            tmp[cin][nn] = (n < NIN) ? xb[(size_t)cin * NIN + n] : 0.f;
        }
        __syncthreads();
        {
            int rl = tid >> 4, c8 = tid & 15;
            int n = nbase + rl;
            float qd = (n < NIN) ? quad[n / WIN] : 0.f;
            ushort w8[8];
            #pragma unroll
            for (int i = 0; i < 8; ++i) w8[i] = f2b(tmp[c8 * 8 + i][rl] * qd);
            int rowi = s * 16 + rl;
            *reinterpret_cast<uint4*>(&As[rowi][(c8 ^ (rowi & 7)) * 8]) = *reinterpret_cast<const uint4*>(w8);
        }
        __syncthreads();
    }
    int w = tid >> 6, lane = tid & 63;
    int l16 = lane & 15, kh = lane >> 4;
    int sa = l16 & 7;
    for (int k = 0; k < KK; ++k) {
        __syncthreads();
        for (int i = tid; i < 1024; i += 256) {
            int rl = i >> 4, c8 = i & 15;
            uint4 v = *reinterpret_cast<const uint4*>(wtb + (((size_t)k * 64 + rl) << 7) + c8 * 8);
            *reinterpret_cast<uint4*>(&Bs[rl][(c8 ^ (rl & 7)) * 8]) = v;
        }
        __syncthreads();
        f32x4v acc[2][4];
        #pragma unroll
        for (int mi = 0; mi < 2; ++mi)
            #pragma unroll
            for (int nf = 0; nf < 4; ++nf) { acc[mi][nf][0] = 0; acc[mi][nf][1] = 0; acc[mi][nf][2] = 0; acc[mi][nf][3] = 0; }
        #pragma unroll
        for (int ks = 0; ks < 4; ++ks) {
            int c8 = ks * 4 + kh;
            s16x8 a0 = *reinterpret_cast<const s16x8*>(&As[w * 32 + l16][(c8 ^ sa) * 8]);
            s16x8 a1 = *reinterpret_cast<const s16x8*>(&As[w * 32 + 16 + l16][(c8 ^ sa) * 8]);
            #pragma unroll
            for (int nf = 0; nf < 4; ++nf) {
                int nn = nf * 16 + l16;
                s16x8 bf = *reinterpret_cast<const s16x8*>(&Bs[nn][(c8 ^ (nn & 7)) * 8]);
                acc[0][nf] = __builtin_amdgcn_mfma_f32_16x16x32_bf16(a0, bf, acc[0][nf], 0, 0, 0);
                acc[1][nf] = __builtin_amdgcn_mfma_f32_16x16x32_bf16(a1, bf, acc[1][nf], 0, 0, 0);
            }
        }
        __syncthreads();
        #pragma unroll
        for (int mi = 0; mi < 2; ++mi) {
            #pragma unroll
            for (int nf = 0; nf < 4; ++nf) {
                int coli = nf * 16 + l16;
                #pragma unroll
                for (int j = 0; j < 4; ++j) {
                    int rowl = w * 32 + mi * 16 + kh * 4 + j;
                    Bo[rowl][((coli >> 3) ^ (rowl & 7)) * 8 + (coli & 7)] = f2b(acc[mi][nf][j]);
                }
            }
        }
        __syncthreads();
        for (int i = tid; i < 1024; i += 256) {
            int rl = i >> 3, u = i & 7;
            int n = n0 + rl;
            if (n < NIN) {
                uint4 v = *reinterpret_cast<const uint4*>(&Bo[rl][(u ^ (rl & 7)) * 8]);
                *reinterpret_cast<uint4*>(xw + (((size_t)(k * NIN + n) * 2 + b) << 6) + u * 8) = v;
            }
        }
    }
}

// ---------------- kGS: fused kSkip (blocks 0..1023) + kGather (blocks 1024..3060) ------------
#define SKIP_BLOCKS 1024
#define GGRID 2037
__global__ __launch_bounds__(256) void kGS(const uint* __restrict__ xw, const int* __restrict__ cnt,
                                           const uint2* __restrict__ csr, ushort* __restrict__ h16,
                                           const float* __restrict__ bd, float* __restrict__ s1,
                                           const float* __restrict__ skip, float* __restrict__ s2) {
    __shared__ float tile[32][33];
    __shared__ float acc4[4];
    __shared__ float red[4][2][8][2];
    int tid = threadIdx.x;
    uint* hw = reinterpret_cast<uint*>(h16);
    if (blockIdx.x < SKIP_BLOCKS) {
        // ---- kSkip path: bx = bid&255, c0 from bit8, b from bit9 ----
        int bx = blockIdx.x & 255;
        int c0 = ((blockIdx.x >> 8) & 1) * 32;
        int b  = blockIdx.x >> 9;
        int tx = tid & 31, ty = tid >> 5;
        if (tid < 4) acc4[tid] = 0.f;
        float sA[2] = {0.f, 0.f}, qA[2] = {0.f, 0.f};
        for (int n0 = bx * 32; n0 < NOUT; n0 += 256 * 32) {
            #pragma unroll
            for (int j = 0; j < 4; ++j) {
                int c = c0 + ty + j * 8, n = n0 + tx;
                if (n < NOUT) {
                    float v = skip[((size_t)b * 64 + c) * NOUT + n];
                    tile[ty + j * 8][tx] = v;
                    int gi = (ty + 8 * j) >> 4;
                    sA[gi] += v; qA[gi] += v * v;
                }
            }
            __syncthreads();
            for (int idx = tid; idx < 512; idx += 256) {
                int nn = idx >> 4, cp = idx & 15;
                int n = n0 + nn;
                if (n < NOUT) {
                    uint st = pk2(tile[cp * 2][nn], tile[cp * 2 + 1][nn]);
                    hw[((size_t)b * NOUT + n) * 64 + 32 + (c0 >> 1) + cp] = st;
                }
            }
            __syncthreads();
        }
        atomicAdd(&acc4[0], sA[0]); atomicAdd(&acc4[1], qA[0]);
        atomicAdd(&acc4[2], sA[1]); atomicAdd(&acc4[3], qA[1]);
        __syncthreads();
        if (tid < 4) {
            int gi = tid >> 1, isq = tid & 1;
            int g = 4 + (c0 >> 4) + gi;
            atomicAdd(&s2[(b * 8 + g) * 2 + isq], acc4[tid]);
        }
        return;
    }
    // ---- kGather path ----
    int gbid = blockIdx.x - SKIP_BLOCKS;
    int lane = tid & 63;
    int wv = tid >> 6;
    int b = lane >> 5;
    int c2 = lane & 31;
    float2 bdv = *reinterpret_cast<const float2*>(&bd[c2 * 2]);
    float sA = 0.f, qA = 0.f;
    for (int r = gbid * 4 + wv; r < NOUT; r += GGRID * 4) {
        int n = min(cnt[r], BCAP);
        float a0 = 0.f, a1 = 0.f;
        const uint2* bucket = csr + (size_t)r * BCAP;
        for (int i = 0; i < n; ++i) {
            uint2 pl = bucket[i];
            int c = pl.x & 0xFFFFF;
            int kk = pl.x >> 20;
            float p = __uint_as_float(pl.y);
            uint v = xw[((size_t)kk * NIN + c) * 64 + lane];
            a0 = fmaf(p, b2f((ushort)(v & 0xFFFF)), a0);
            a1 = fmaf(p, b2f((ushort)(v >> 16)), a1);
        }
        hw[((size_t)b * NOUT + r) * 64 + c2] = pk2(a0, a1);
        float y0 = a0 + bdv.x, y1 = a1 + bdv.y;
        sA += y0 + y1; qA += y0 * y0 + y1 * y1;
    }
    #pragma unroll
    for (int o = 1; o <= 2; o <<= 1) { sA += __shfl_xor(sA, o); qA += __shfl_xor(qA, o); }
    if ((lane & 3) == 0) {
        red[wv][b][c2 >> 2][0] = sA;
        red[wv][b][c2 >> 2][1] = qA;
    }
    __syncthreads();
    if (tid < 32) {
        int bb = tid >> 4, g = (tid >> 1) & 7, isq = tid & 1;
        float v = red[0][bb][g][isq] + red[1][bb][g][isq] + red[2][bb][g][isq] + red[3][bb][g][isq];
        atomicAdd(&s1[(bb * 8 + g) * 2 + isq], v);
    }
}

// ---------------- kApply1: GN1 + GELU in place (bf16 h); fused GN2 stats groups 0..3 ---------
#define AGRID 2048
__global__ __launch_bounds__(256) void kApply1(ushort* __restrict__ h16, const float* __restrict__ bd,
                                               const float* __restrict__ g1, const float* __restrict__ b1,
                                               const float* __restrict__ s1, float* __restrict__ s2) {
    int tid = threadIdx.x;
    int c8g = tid & 7;
    int lane = tid & 63, wv = tid >> 6;
    const float invc = 1.0f / (8.0f * NOUT);
    float mu0 = s1[c8g * 2] * invc;
    float r0 = rsqrtf(s1[c8g * 2 + 1] * invc - mu0 * mu0 + EPS_);
    float mu1 = s1[(8 + c8g) * 2] * invc;
    float r1 = rsqrtf(s1[(8 + c8g) * 2 + 1] * invc - mu1 * mu1 + EPS_);
    float bdv[8], g1v[8], b1v[8];
    #pragma unroll
    for (int j = 0; j < 8; ++j) {
        int c = c8g * 8 + j;
        bdv[j] = bd[c]; g1v[j] = g1[c]; b1v[j] = b1[c];
    }
    float sA[2] = {0.f, 0.f}, qA[2] = {0.f, 0.f};
    const size_t total = (size_t)B_ * NOUT * 8;
    uint4* hb = reinterpret_cast<uint4*>(h16);
    for (size_t idx = (size_t)blockIdx.x * 256 + tid; idx < total; idx += (size_t)AGRID * 256) {
        size_t pn = idx >> 3;
        int b = pn >= (size_t)NOUT;
        float mu = b ? mu1 : mu0, rstd = b ? r1 : r0;
        uint4* p = hb + pn * 16 + c8g;
        uint4 hv = *p;
        const ushort* hs = reinterpret_cast<const ushort*>(&hv);
        float ls = 0.f, lq = 0.f;
        uint outw[4];
        #pragma unroll
        for (int jp = 0; jp < 4; ++jp) {
            float a0 = b2f(hs[jp * 2]) + bdv[jp * 2];
            float a1 = b2f(hs[jp * 2 + 1]) + bdv[jp * 2 + 1];
            float t0 = (a0 - mu) * rstd * g1v[jp * 2] + b1v[jp * 2];
            float t1 = (a1 - mu) * rstd * g1v[jp * 2 + 1] + b1v[jp * 2 + 1];
            float ge0 = t0 * 0.5f * (1.0f + erff(t0 * 0.70710678118654752f));
            float ge1 = t1 * 0.5f * (1.0f + erff(t1 * 0.70710678118654752f));
            ls += ge0 + ge1; lq += ge0 * ge0 + ge1 * ge1;
            outw[jp] = pk2(ge0, ge1);
        }
        sA[b] += ls; qA[b] += lq;
        uint4 st = {outw[0], outw[1], outw[2], outw[3]};
        *p = st;
    }
    #pragma unroll
    for (int o = 8; o <= 32; o <<= 1) {
        sA[0] += __shfl_xor(sA[0], o); qA[0] += __shfl_xor(qA[0], o);
        sA[1] += __shfl_xor(sA[1], o); qA[1] += __shfl_xor(qA[1], o);
    }
    sA[0] += __shfl_xor(sA[0], 1); qA[0] += __shfl_xor(qA[0], 1);
    sA[1] += __shfl_xor(sA[1], 1); qA[1] += __shfl_xor(qA[1], 1);
    __shared__ float red[4][4][4];
    if (lane < 8 && !(lane & 1)) {
        int g = lane >> 1;
        red[wv][g][0] = sA[0]; red[wv][g][1] = qA[0];
        red[wv][g][2] = sA[1]; red[wv][g][3] = qA[1];
    }
    __syncthreads();
    if (tid < 16) {
        int g = tid >> 2, q = tid & 3;
        float v = red[0][g][q] + red[1][g][q] + red[2][g][q] + red[3][g][q];
        int b = q >> 1, isq = q & 1;
        atomicAdd(&s2[(b * 8 + g) * 2 + isq], v);
    }
}

// ---------------- kQKV: one h pass (bf16), swizzled LDS, 3 output chunks ---------------------
__global__ __launch_bounds__(256) void kQKV(const ushort* __restrict__ h16, const ushort* __restrict__ wqt,
                                            const float* __restrict__ bqkv, const float* __restrict__ g2,
                                            const float* __restrict__ b2, const float* __restrict__ s2,
                                            ushort* __restrict__ qg, ushort* __restrict__ kg,
                                            ushort* __restrict__ vtg) {
    __shared__ ushort As[128][128];
    __shared__ ushort Bs[128][128];
    __shared__ float muT[16], rsT[16], g2T[128], b2T[128];
    int tid = threadIdx.x;
    size_t r0 = (size_t)blockIdx.x * 128;
    const float invc2 = 1.0f / (16.0f * NOUT);
    if (tid < 16) {
        float mu = s2[tid * 2] * invc2;
        float ex2 = s2[tid * 2 + 1] * invc2;
        muT[tid] = mu;
        rsT[tid] = rsqrtf(ex2 - mu * mu + EPS_);
    }
    if (tid < 128) { g2T[tid] = g2[tid]; b2T[tid] = b2[tid]; }
    __syncthreads();
    const uint4* hb = reinterpret_cast<const uint4*>(h16);
    for (int i = tid; i < 2048; i += 256) {
        int rl = i >> 4, c8 = i & 15;
        size_t rg = r0 + rl;
        uint4 wv = {0, 0, 0, 0};
        if (rg < PTOT) {
            int c = c8 * 8;
            int g = ((rg >= (size_t)NOUT) ? 8 : 0) + (c >> 4);
            float mu = muT[g], rs = rsT[g];
            uint4 hv = hb[rg * 16 + c8];
            const ushort* hs = reinterpret_cast<const ushort*>(&hv);
            float t[8];
            #pragma unroll
            for (int j = 0; j < 8; ++j)
                t[j] = (b2f(hs[j]) - mu) * rs * g2T[c + j] + b2T[c + j];
            wv.x = pk2(t[0], t[1]); wv.y = pk2(t[2], t[3]);
            wv.z = pk2(t[4], t[5]); wv.w = pk2(t[6], t[7]);
        }
        *reinterpret_cast<uint4*>(&As[rl][(c8 ^ (rl & 7)) * 8]) = wv;
    }
    int w = tid >> 6, lane = tid & 63;
    int l16 = lane & 15, kh = lane >> 4;
    int sa = l16 & 7;
    for (int n0 = 0; n0 < 384; n0 += 128) {
        __syncthreads();
        for (int i = tid; i < 2048; i += 256) {
            int rl = i >> 4, c8 = i & 15;
            uint4 v = *reinterpret_cast<const uint4*>(wqt + ((size_t)(n0 + rl) << 7) + c8 * 8);
            *reinterpret_cast<uint4*>(&Bs[rl][(c8 ^ (rl & 7)) * 8]) = v;
        }
        __syncthreads();
        f32x4v acc[2][8];
        #pragma unroll
        for (int mi = 0; mi < 2; ++mi)
            #pragma unroll
            for (int nf = 0; nf < 8; ++nf) { acc[mi][nf][0] = 0; acc[mi][nf][1] = 0; acc[mi][nf][2] = 0; acc[mi][nf][3] = 0; }
        #pragma unroll
        for (int ks = 0; ks < 4; ++ks) {
            int c8 = ks * 4 + kh;
            s16x8 a0 = *reinterpret_cast<const s16x8*>(&As[w * 32 + l16][(c8 ^ sa) * 8]);
            s16x8 a1 = *reinterpret_cast<const s16x8*>(&As[w * 32 + 16 + l16][(c8 ^ sa) * 8]);
            #pragma unroll
            for (int nf = 0; nf < 8; ++nf) {
                int nn = nf * 16 + l16;
                s16x8 bf = *reinterpret_cast<const s16x8*>(&Bs[nn][(c8 ^ (nn & 7)) * 8]);
                acc[0][nf] = __builtin_amdgcn_mfma_f32_16x16x32_bf16(a0, bf, acc[0][nf], 0, 0, 0);
                acc[1][nf] = __builtin_amdgcn_mfma_f32_16x16x32_bf16(a1, bf, acc[1][nf], 0, 0, 0);
            }
        }
        if (n0 < 256) {
            __syncthreads();
            const float bscale = (n0 == 0) ? QSCALE : 1.0f;
            #pragma unroll
            for (int mi = 0; mi < 2; ++mi) {
                #pragma unroll
                for (int nf = 0; nf < 8; ++nf) {
                    int coli = nf * 16 + l16;
                    float bias = bqkv[n0 + coli] * bscale;
                    #pragma unroll
                    for (int j = 0; j < 4; ++j) {
                        int rowl = w * 32 + mi * 16 + kh * 4 + j;
                        Bs[rowl][((coli >> 3) ^ (rowl & 7)) * 8 + (coli & 7)] = f2b(acc[mi][nf][j] + bias);
                    }
                }
            }
            __syncthreads();
            ushort* dst = (n0 == 0) ? qg : kg;
            for (int i = tid; i < 2048; i += 256) {
                int rl = i >> 4, c8 = i & 15;
                size_t rg = r0 + rl;
                if (rg < PTOT) {
                    uint4 v = *reinterpret_cast<const uint4*>(&Bs[rl][(c8 ^ (rl & 7)) * 8]);
                    *(reinterpret_cast<uint4*>(dst) + rg * 16 + c8) = v;
                }
            }
        } else {
            #pragma unroll
            for (int mi = 0; mi < 2; ++mi) {
                size_t rg0 = r0 + w * 32 + mi * 16 + kh * 4;
                if (rg0 < PTOT) {
                    int b = rg0 >= (size_t)NOUT;
                    size_t n = rg0 - (size_t)b * NOUT;
                    #pragma unroll
                    for (int nf = 0; nf < 8; ++nf) {
                        int coli = nf * 16 + l16;
                        float bias = bqkv[256 + coli];
                        uint2 st = { pk2(acc[mi][nf][0] + bias, acc[mi][nf][1] + bias),
                                     pk2(acc[mi][nf][2] + bias, acc[mi][nf][3] + bias) };
                        *reinterpret_cast<uint2*>(&vtg[((size_t)(b * 128 + coli)) * NOUT + n]) = st;
                    }
                }
            }
        }
    }
}

// ---------------- kAttn: V in LDS, kt-outer loop feeds BOTH q-tiles per K/V fragment ---------
__global__ __launch_bounds__(384) void kAttn(const ushort* __restrict__ qg, const ushort* __restrict__ kg,
                                             const ushort* __restrict__ vtg, ushort* __restrict__ og) {
    __shared__ ushort K_sm[360][40];   // 28.8 KB
    __shared__ ushort V_sm[32][392];   // 25.1 KB; total 53.9 KB
    int head = blockIdx.x, ring = blockIdx.y, b = blockIdx.z;
    int tid = threadIdx.x;
    size_t rowbase = (size_t)b * NOUT + (size_t)ring * 360;
    for (int i = tid; i < 1440; i += 384) {
        int r = i >> 2, c = (i & 3) * 8;
        uint4 val = *reinterpret_cast<const uint4*>(kg + (rowbase + r) * 128 + head * 32 + c);
        *reinterpret_cast<uint4*>(&K_sm[r][c]) = val;
    }
    {
        int d = tid / 12, j = tid % 12;
        const ushort* vp = vtg + ((size_t)(b * 128 + head * 32 + d)) * NOUT + (size_t)ring * 360;
        for (int c8 = j; c8 < 49; c8 += 12) {
            uint4 val = {0, 0, 0, 0};
            if (c8 < 45) val = *reinterpret_cast<const uint4*>(vp + c8 * 8);
            *reinterpret_cast<uint4*>(&V_sm[d][c8 * 8]) = val;
        }
    }
    __syncthreads();
    int wv = tid >> 6, lane = tid & 63;
    int lq = lane & 31, hi = lane >> 5;
    s16x8 qa[2], qb[2];
    bool qok[2];
    int qvv[2];
    #pragma unroll
    for (int qi = 0; qi < 2; ++qi) {
        int qt = wv + qi * 6;
        qvv[qi] = qt * 32 + lq;
        qok[qi] = qvv[qi] < 360;
        uint4 qf1 = {0, 0, 0, 0}, qf2 = {0, 0, 0, 0};
        if (qok[qi]) {
            const ushort* qp = qg + (rowbase + qvv[qi]) * 128 + head * 32;
            qf1 = *reinterpret_cast<const uint4*>(qp + hi * 8);
            qf2 = *reinterpret_cast<const uint4*>(qp + 16 + hi * 8);
        }
        qa[qi] = __builtin_bit_cast(s16x8, qf1);
        qb[qi] = __builtin_bit_cast(s16x8, qf2);
    }
    f32x16v O[2];
    #pragma unroll
    for (int qi = 0; qi < 2; ++qi)
        #pragma unroll
        for (int r2 = 0; r2 < 16; ++r2) O[qi][r2] = 0.f;
    float ls0[2] = {0.f, 0.f}, ls1[2] = {0.f, 0.f};
    #pragma unroll 1
    for (int kt = 0; kt < 12; ++kt) {
        int krow = min(kt * 32 + lq, 359);
        s16x8 ka = *reinterpret_cast<const s16x8*>(&K_sm[krow][hi * 8]);
        s16x8 kb = *reinterpret_cast<const s16x8*>(&K_sm[krow][16 + hi * 8]);
        s16x8 va = *reinterpret_cast<const s16x8*>(&V_sm[lq][kt * 32 + hi * 8]);
        s16x8 vb = *reinterpret_cast<const s16x8*>(&V_sm[lq][kt * 32 + 16 + hi * 8]);
        #pragma unroll
        for (int qi = 0; qi < 2; ++qi) {
            f32x16v S;
            #pragma unroll
            for (int r2 = 0; r2 < 16; ++r2) S[r2] = 0.f;
            S = __builtin_amdgcn_mfma_f32_32x32x16_bf16(ka, qa[qi], S, 0, 0, 0);
            S = __builtin_amdgcn_mfma_f32_32x32x16_bf16(kb, qb[qi], S, 0, 0, 0);
            if (kt == 11) {
                #pragma unroll
                for (int r2 = 4; r2 < 16; ++r2) S[r2] = -1e30f;
            }
            uint pw[8];
            #pragma unroll
            for (int pr = 0; pr < 8; ++pr) {
                float e0 = __builtin_amdgcn_exp2f(S[pr * 2]);
                float e1 = __builtin_amdgcn_exp2f(S[pr * 2 + 1]);
                pw[pr] = pk2(e0, e1);
                if (pr & 1) ls1[qi] += e0 + e1; else ls0[qi] += e0 + e1;
            }
            i32x2v r01 = __builtin_amdgcn_permlane32_swap((int)pw[0], (int)pw[2], false, false);
            i32x2v r11 = __builtin_amdgcn_permlane32_swap((int)pw[1], (int)pw[3], false, false);
            i32x2v r21 = __builtin_amdgcn_permlane32_swap((int)pw[4], (int)pw[6], false, false);
            i32x2v r31 = __builtin_amdgcn_permlane32_swap((int)pw[5], (int)pw[7], false, false);
            uint4 pf1u = {(uint)r01[0], (uint)r11[0], (uint)r01[1], (uint)r11[1]};
            uint4 pf2u = {(uint)r21[0], (uint)r31[0], (uint)r21[1], (uint)r31[1]};
            O[qi] = __builtin_amdgcn_mfma_f32_32x32x16_bf16(va, __builtin_bit_cast(s16x8, pf1u), O[qi], 0, 0, 0);
            O[qi] = __builtin_amdgcn_mfma_f32_32x32x16_bf16(vb, __builtin_bit_cast(s16x8, pf2u), O[qi], 0, 0, 0);
        }
        __builtin_amdgcn_sched_barrier(0);
    }
    #pragma unroll
    for (int qi = 0; qi < 2; ++qi) {
        float lsum = ls0[qi] + ls1[qi];
        i32x2v sw = __builtin_amdgcn_permlane32_swap(__float_as_int(lsum), __float_as_int(lsum), false, false);
        lsum = __int_as_float(sw[0]) + __int_as_float(sw[1]);
        float inv = 1.f / lsum;
        if (qok[qi]) {
            ushort* op = og + (rowbase + qvv[qi]) * 128 + head * 32;
            #pragma unroll
            for (int g4 = 0; g4 < 4; ++g4) {
                int dbase = g4 * 8 + hi * 4;
                uint w0 = pk2(O[qi][g4 * 4 + 0] * inv, O[qi][g4 * 4 + 1] * inv);
                uint w1 = pk2(O[qi][g4 * 4 + 2] * inv, O[qi][g4 * 4 + 3] * inv);
                uint2 st = {w0, w1};
                *reinterpret_cast<uint2*>(op + dbase) = st;
            }
        }
    }
}

// ---------------- kFinal (MFMA): out[b][c][n] = (o @ wo)[n][c] + bo[c] + h[b][n][c] ----------
__global__ __launch_bounds__(256) void kFinal(const ushort* __restrict__ ob, const ushort* __restrict__ wot,
                                              const float* __restrict__ bo, const ushort* __restrict__ h16,
                                              float* __restrict__ out) {
    __shared__ ushort AB[2][128][128];
    int tid = threadIdx.x;
    size_t r0 = (size_t)blockIdx.x * 128;
    for (int i = tid; i < 2048; i += 256) {
        int rl = i >> 4, c8 = i & 15;
        size_t rg = r0 + rl;
        uint4 v = {0, 0, 0, 0};
        if (rg < PTOT) v = *reinterpret_cast<const uint4*>(ob + (rg << 7) + c8 * 8);
        *reinterpret_cast<uint4*>(&AB[0][rl][(c8 ^ (rl & 7)) * 8]) = v;
    }
    for (int i = tid; i < 2048; i += 256) {
        int rl = i >> 4, c8 = i & 15;
        uint4 v = *reinterpret_cast<const uint4*>(wot + ((size_t)rl << 7) + c8 * 8);
        *reinterpret_cast<uint4*>(&AB[1][rl][(c8 ^ (rl & 7)) * 8]) = v;
    }
    __syncthreads();
    int w = tid >> 6, lane = tid & 63;
    int l16 = lane & 15, kh = lane >> 4;
    int sa = l16 & 7;
    f32x4v acc[2][8];
    #pragma unroll
    for (int mi = 0; mi < 2; ++mi)
        #pragma unroll
        for (int nf = 0; nf < 8; ++nf) { acc[mi][nf][0] = 0; acc[mi][nf][1] = 0; acc[mi][nf][2] = 0; acc[mi][nf][3] = 0; }
    #pragma unroll
    for (int ks = 0; ks < 4; ++ks) {
        int c8 = ks * 4 + kh;
        s16x8 a0 = *reinterpret_cast<const s16x8*>(&AB[0][w * 32 + l16][(c8 ^ sa) * 8]);
        s16x8 a1 = *reinterpret_cast<const s16x8*>(&AB[0][w * 32 + 16 + l16][(c8 ^ sa) * 8]);
        #pragma unroll
        for (int nf = 0; nf < 8; ++nf) {
            int nn = nf * 16 + l16;
            s16x8 bf = *reinterpret_cast<const s16x8*>(&AB[1][nn][(c8 ^ (nn & 7)) * 8]);
            acc[0][nf] = __builtin_amdgcn_mfma_f32_16x16x32_bf16(a0, bf, acc[0][nf], 0, 0, 0);
            acc[1][nf] = __builtin_amdgcn_mfma_f32_16x16x32_bf16(a1, bf, acc[1][nf], 0, 0, 0);
        }
    }
    float* trf = reinterpret_cast<float*>(&AB[0][0][0]);
    const uint* h32 = reinterpret_cast<const uint*>(h16);
    int hw = w >> 1;
    for (int half = 0; half < 2; ++half) {
        __syncthreads();
        if (hw == half) {
            #pragma unroll
            for (int mi = 0; mi < 2; ++mi) {
                #pragma unroll
                for (int nf = 0; nf < 8; ++nf) {
                    int coli = nf * 16 + l16;
                    float bv = bo[coli];
                    #pragma unroll
                    for (int j = 0; j < 4; ++j) {
                        int relrow = (w & 1) * 32 + mi * 16 + kh * 4 + j;
                        trf[relrow * 129 + coli] = acc[mi][nf][j] + bv;
                    }
                }
            }
        }
        __syncthreads();
        for (int i = tid; i < 4096; i += 256) {
            int rl = i >> 6, c2 = i & 63;
            size_t p = r0 + half * 64 + rl;
            if (p < PTOT) {
                uint hv = h32[p * 64 + c2];
                trf[rl * 129 + c2 * 2]     += b2f((ushort)(hv & 0xFFFF));
                trf[rl * 129 + c2 * 2 + 1] += b2f((ushort)(hv >> 16));
            }
        }
        __syncthreads();
        for (int i = tid; i < 8192; i += 256) {
            int c = i >> 6, rl = i & 63;
            size_t p = r0 + half * 64 + rl;
            if (p < PTOT) {
                int b = p >= (size_t)NOUT;
                size_t n = p - (size_t)b * NOUT;
                out[((size_t)(b * 128 + c)) * NOUT + n] = trf[rl * 129 + c];
            }
        }
    }
}

extern "C" void kernel_launch(void* const* d_in, const int* in_sizes, int n_in,
                              void* d_out, int out_size, void* d_ws, size_t ws_size,
                              hipStream_t stream) {
    const float* x    = (const float*)d_in[0];
    const float* skip = (const float*)d_in[1];
    const float* wd   = (const float*)d_in[2];
    const float* bd   = (const float*)d_in[3];
    const float* psi  = (const float*)d_in[4];
    const float* quad = (const float*)d_in[5];
    const float* g1   = (const float*)d_in[6];
    const float* b1   = (const float*)d_in[7];
    const float* g2   = (const float*)d_in[8];
    const float* b2   = (const float*)d_in[9];
    const float* wqkv = (const float*)d_in[10];
    const float* bqkv = (const float*)d_in[11];
    const float* wo   = (const float*)d_in[12];
    const float* bo   = (const float*)d_in[13];
    const int* row    = (const int*)d_in[14];
    const int* col    = (const int*)d_in[15];
    const int* ker    = (const int*)d_in[16];
    float* ws = (float*)d_ws;
    ushort* xw = (ushort*)ws;                // phase 1: bf16 [K][NIN][B][64]
    ushort* h16 = (ushort*)(ws + OFF_H);     // bf16 [PTOT][128]
    float* s1 = ws + OFF_S1;
    float* s2 = ws + OFF_S2;
    ushort* wtb = (ushort*)(ws + OFF_WT);
    int*   cnt = (int*)(ws + OFF_CNT);
    uint2* csr = (uint2*)(ws + OFF_CSR);
    ushort* qb  = (ushort*)(ws + OFF_Q);
    ushort* kb  = (ushort*)(ws + OFF_K);
    ushort* vtb = (ushort*)(ws + OFF_VT);
    ushort* wot = (ushort*)(ws + OFF_WOT);
    ushort* wqt = (ushort*)d_out;            // scratch: fully overwritten by kFinal
    float* out = (float*)d_out;

    hipMemsetAsync(s1, 0, 64 * sizeof(float), stream);      // s1 + s2
    hipMemsetAsync(cnt, 0, 65536 * sizeof(int), stream);

    kT<<<544, 256, 0, stream>>>(wd, wqkv, wo, wtb, wqt, wot);
    kAF<<<KA_BLOCKS + 2037, 256, 0, stream>>>(x, wtb, quad, xw, row, col, ker, psi, cnt, csr);
    kGS<<<SKIP_BLOCKS + GGRID, 256, 0, stream>>>((const uint*)xw, cnt, csr, h16, bd, s1, skip, s2);
    kApply1<<<AGRID, 256, 0, stream>>>(h16, bd, g1, b1, s1, s2);
    kQKV<<<(int)((PTOT + 127) / 128), 256, 0, stream>>>(h16, wqt, bqkv, g2, b2, s2, qb, kb, vtb);
    kAttn<<<dim3(NH, HOUT, B_), 384, 0, stream>>>(qb, kb, vtb, qb /*o aliases q*/);
    kFinal<<<(int)((PTOT + 127) / 128), 256, 0, stream>>>(qb, wot, bo, h16, out);
}

// Round 18
// 360.076 us; speedup vs baseline: 1.1873x; 1.0641x over previous
//
#include <hip/hip_runtime.h>
#include <hip/hip_bf16.h>

#define B_ 2
#define CIN 128
#define HIN 91
#define WIN 180
#define NIN (HIN*WIN)         // 16380
#define COUT_ 64
#define HOUT 181
#define WOUT 360
#define NOUT (HOUT*WOUT)      // 65160
#define KK 9
#define NNZ_ (NOUT*8)         // 521280
#define CTOT 128
#define NH 4
#define HD 32
#define EPS_ 1e-5f
#define PTOT ((size_t)B_*NOUT)   // 130320
#define BCAP 40

// q pre-scale: 1/sqrt(32) * log2(e)  -> scores are in log2 domain; softmax uses exp2
#define QSCALE (0.17677669529663688f * 1.4426950408889634f)

typedef short s16x8 __attribute__((ext_vector_type(8)));
typedef float f32x4v __attribute__((ext_vector_type(4)));
typedef float f32x16v __attribute__((ext_vector_type(16)));
typedef int i32x2v __attribute__((ext_vector_type(2)));

// workspace layout (float offsets); h is bf16 [PTOT][128]
#define OFF_Q  ((size_t)0)
#define OFF_K  ((size_t)8340480)
#define OFF_WOT ((size_t)16680960)                   // wot bf16 [128][128]
#define OFF_H  ((size_t)18869760)
#define OFF_S1 (OFF_H + (size_t)B_*NOUT*CTOT)        // 35550720
#define OFF_S2 (OFF_S1 + 32)
#define OFF_WT (OFF_S2 + 32)                         // wtb bf16 [K][64][128]
#define OFF_VT (OFF_WT + (size_t)KK*CIN*COUT_)       // vt bf16
#define OFF_CNT OFF_VT                               // 65536 ints (aliases vt)
#define OFF_CSR (OFF_VT + 65536)                     // NOUT*BCAP uint2 (aliases vt)

__device__ inline ushort f2b(float x) { return __bfloat16_as_ushort(__float2bfloat16(x)); }
__device__ inline float b2f(ushort u) { return __bfloat162float(__ushort_as_bfloat16(u)); }
__device__ inline uint pk2(float lo, float hi) {
    return (uint)f2b(lo) | ((uint)f2b(hi) << 16);
}

// ---------------- kT: weight transposes (one-shot) -------------------------------------------
__global__ __launch_bounds__(256) void kT(const float* __restrict__ wd, const float* __restrict__ wqkv,
                                          const float* __restrict__ wo, ushort* __restrict__ wtb,
                                          ushort* __restrict__ wqt, ushort* __restrict__ wot) {
    int idx = blockIdx.x * 256 + threadIdx.x;
    if (idx < KK * CIN * COUT_) {
        int cin = idx & 127;
        int rest = idx >> 7;
        int cout = rest & 63;
        int k = rest >> 6;
        wtb[idx] = f2b(wd[((size_t)cout * CIN + cin) * KK + k]);
    } else if (idx < KK * CIN * COUT_ + 384 * 128) {
        int i2 = idx - KK * CIN * COUT_;
        int n = i2 >> 7, kk = i2 & 127;
        float v = wqkv[(size_t)kk * 384 + n];
        if (n < 128) v *= QSCALE;   // fold q-scale * log2(e)
        wqt[i2] = f2b(v);
    } else {
        int i3 = idx - (KK * CIN * COUT_ + 384 * 128);
        if (i3 < 128 * 128) {
            int n = i3 >> 7, kk = i3 & 127;
            wot[i3] = f2b(wo[(size_t)kk * 128 + n]);
        }
    }
}

// ---------------- kAF: fused kA (0..255) + kSkip (256..1279) + kFill (1280..3316) ------------
#define KA_BLOCKS 256
#define SKIP_BASE 256
#define FILL_BASE 1280
__global__ __launch_bounds__(256) void kAF(const float* __restrict__ x, const ushort* __restrict__ wtb,
                                           const float* __restrict__ quad, ushort* __restrict__ xw,
                                           const int* __restrict__ row, const int* __restrict__ col,
                                           const int* __restrict__ ker, const float* __restrict__ psi,
                                           int* __restrict__ cnt, uint2* __restrict__ csr,
                                           const float* __restrict__ skip, ushort* __restrict__ h16,
                                           float* __restrict__ s2) {
    __shared__ ushort As[128][128];              // 32 KB (kA path only)
    __shared__ __align__(16) char buf[16384];
    int tid = threadIdx.x;
    if (blockIdx.x >= FILL_BASE) {
        // ---- kFill path ----
        int e = (blockIdx.x - FILL_BASE) * 256 + tid;
        if (e < NNZ_) {
            int r = row[e];
            int pos = atomicAdd(&cnt[r], 1);
            if (pos < BCAP) {
                uint2 pl;
                pl.x = (uint)col[e] | ((uint)ker[e] << 20);
                pl.y = __float_as_uint(psi[e]);
                csr[(size_t)r * BCAP + pos] = pl;
            }
        }
        return;
    }
    if (blockIdx.x >= SKIP_BASE) {
        // ---- kSkip path (transpose + GN2 stats groups 4..7) ----
        float (*tile)[33] = reinterpret_cast<float(*)[33]>(buf);        // 32x33 f32
        float* acc4 = reinterpret_cast<float*>(buf + 32 * 33 * 4);      // 4 f32
        int idx4 = blockIdx.x - SKIP_BASE;
        int bx = idx4 & 255;
        int c0 = ((idx4 >> 8) & 1) * 32;
        int b  = idx4 >> 9;
        int tx = tid & 31, ty = tid >> 5;
        if (tid < 4) acc4[tid] = 0.f;
        float sA[2] = {0.f, 0.f}, qA[2] = {0.f, 0.f};
        uint* hw = reinterpret_cast<uint*>(h16);
        for (int n0 = bx * 32; n0 < NOUT; n0 += 256 * 32) {
            #pragma unroll
            for (int j = 0; j < 4; ++j) {
                int c = c0 + ty + j * 8, n = n0 + tx;
                if (n < NOUT) {
                    float v = skip[((size_t)b * 64 + c) * NOUT + n];
                    tile[ty + j * 8][tx] = v;
                    int gi = (ty + 8 * j) >> 4;
                    sA[gi] += v; qA[gi] += v * v;
                }
            }
            __syncthreads();
            for (int idx = tid; idx < 512; idx += 256) {
                int nn = idx >> 4, cp = idx & 15;
                int n = n0 + nn;
                if (n < NOUT) {
                    uint st = pk2(tile[cp * 2][nn], tile[cp * 2 + 1][nn]);
                    hw[((size_t)b * NOUT + n) * 64 + 32 + (c0 >> 1) + cp] = st;
                }
            }
            __syncthreads();
        }
        atomicAdd(&acc4[0], sA[0]); atomicAdd(&acc4[1], qA[0]);
        atomicAdd(&acc4[2], sA[1]); atomicAdd(&acc4[3], qA[1]);
        __syncthreads();
        if (tid < 4) {
            int gi = tid >> 1, isq = tid & 1;
            int g = 4 + (c0 >> 4) + gi;
            atomicAdd(&s2[(b * 8 + g) * 2 + isq], acc4[tid]);
        }
        return;
    }
    // ---- kA path ----
    ushort (*Bs)[128] = reinterpret_cast<ushort(*)[128]>(buf);
    ushort (*Bo)[64]  = reinterpret_cast<ushort(*)[64]>(buf);
    float  (*tmp)[17] = reinterpret_cast<float(*)[17]>(buf);
    int n0 = (blockIdx.x & 127) * 128;
    int b  = blockIdx.x >> 7;
    const float* xb = x + (size_t)b * CIN * NIN;
    for (int s = 0; s < 8; ++s) {
        int nbase = n0 + s * 16;
        for (int idx = tid; idx < 128 * 16; idx += 256) {
            int cin = idx >> 4, nn = idx & 15;
            int n = nbase + nn;
            tmp[cin][nn] = (n < NIN) ? xb[(size_t)cin * NIN + n] : 0.f;
        }
        __syncthreads();
        {
            int rl = tid >> 4, c8 = tid & 15;
            int n = nbase + rl;
            float qd = (n < NIN) ? quad[n / WIN] : 0.f;
            ushort w8[8];
            #pragma unroll
            for (int i = 0; i < 8; ++i) w8[i] = f2b(tmp[c8 * 8 + i][rl] * qd);
            int rowi = s * 16 + rl;
            *reinterpret_cast<uint4*>(&As[rowi][(c8 ^ (rowi & 7)) * 8]) = *reinterpret_cast<const uint4*>(w8);
        }
        __syncthreads();
    }
    int w = tid >> 6, lane = tid & 63;
    int l16 = lane & 15, kh = lane >> 4;
    int sa = l16 & 7;
    for (int k = 0; k < KK; ++k) {
        __syncthreads();
        for (int i = tid; i < 1024; i += 256) {
            int rl = i >> 4, c8 = i & 15;
            uint4 v = *reinterpret_cast<const uint4*>(wtb + (((size_t)k * 64 + rl) << 7) + c8 * 8);
            *reinterpret_cast<uint4*>(&Bs[rl][(c8 ^ (rl & 7)) * 8]) = v;
        }
        __syncthreads();
        f32x4v acc[2][4];
        #pragma unroll
        for (int mi = 0; mi < 2; ++mi)
            #pragma unroll
            for (int nf = 0; nf < 4; ++nf) { acc[mi][nf][0] = 0; acc[mi][nf][1] = 0; acc[mi][nf][2] = 0; acc[mi][nf][3] = 0; }
        #pragma unroll
        for (int ks = 0; ks < 4; ++ks) {
            int c8 = ks * 4 + kh;
            s16x8 a0 = *reinterpret_cast<const s16x8*>(&As[w * 32 + l16][(c8 ^ sa) * 8]);
            s16x8 a1 = *reinterpret_cast<const s16x8*>(&As[w * 32 + 16 + l16][(c8 ^ sa) * 8]);
            #pragma unroll
            for (int nf = 0; nf < 4; ++nf) {
                int nn = nf * 16 + l16;
                s16x8 bf = *reinterpret_cast<const s16x8*>(&Bs[nn][(c8 ^ (nn & 7)) * 8]);
                acc[0][nf] = __builtin_amdgcn_mfma_f32_16x16x32_bf16(a0, bf, acc[0][nf], 0, 0, 0);
                acc[1][nf] = __builtin_amdgcn_mfma_f32_16x16x32_bf16(a1, bf, acc[1][nf], 0, 0, 0);
            }
        }
        __syncthreads();
        #pragma unroll
        for (int mi = 0; mi < 2; ++mi) {
            #pragma unroll
            for (int nf = 0; nf < 4; ++nf) {
                int coli = nf * 16 + l16;
                #pragma unroll
                for (int j = 0; j < 4; ++j) {
                    int rowl = w * 32 + mi * 16 + kh * 4 + j;
                    Bo[rowl][((coli >> 3) ^ (rowl & 7)) * 8 + (coli & 7)] = f2b(acc[mi][nf][j]);
                }
            }
        }
        __syncthreads();
        for (int i = tid; i < 1024; i += 256) {
            int rl = i >> 3, u = i & 7;
            int n = n0 + rl;
            if (n < NIN) {
                uint4 v = *reinterpret_cast<const uint4*>(&Bo[rl][(u ^ (rl & 7)) * 8]);
                *reinterpret_cast<uint4*>(xw + (((size_t)(k * NIN + n) * 2 + b) << 6) + u * 8) = v;
            }
        }
    }
}

// ---------------- kGather: batched MLP (8 concurrent loads) + fused GN1 stats ----------------
#define GGRID 2037
__global__ __launch_bounds__(256) void kGather(const uint* __restrict__ xw, const int* __restrict__ cnt,
                                               const uint2* __restrict__ csr, ushort* __restrict__ h16,
                                               const float* __restrict__ bd, float* __restrict__ s1) {
    int tid = threadIdx.x;
    int lane = tid & 63;
    int wv = tid >> 6;
    int b = lane >> 5;
    int c2 = lane & 31;
    float2 bdv = *reinterpret_cast<const float2*>(&bd[c2 * 2]);
    float sA = 0.f, qA = 0.f;
    uint* hw = reinterpret_cast<uint*>(h16);
    for (int r = blockIdx.x * 4 + wv; r < NOUT; r += GGRID * 4) {
        int n = min(cnt[r], BCAP);
        const uint2* bucket = csr + (size_t)r * BCAP;
        float a0 = 0.f, a1 = 0.f;
        // batch: first 8 entries issued concurrently (addresses clamped, p masked for i>=n).
        // clamped loads read xw[lane] (valid, finite) * p=0 -> exact 0 contribution.
        uint2 pl[8];
        #pragma unroll
        for (int i = 0; i < 8; ++i) pl[i] = bucket[i];   // always within csr allocation (BCAP=40)
        uint v[8];
        #pragma unroll
        for (int i = 0; i < 8; ++i) {
            size_t base = ((size_t)(pl[i].x >> 20) * NIN + (pl[i].x & 0xFFFFF)) * 64 + lane;
            v[i] = xw[(i < n) ? base : (size_t)lane];
        }
        #pragma unroll
        for (int i = 0; i < 8; ++i) {
            float p = (i < n) ? __uint_as_float(pl[i].y) : 0.f;
            a0 = fmaf(p, b2f((ushort)(v[i] & 0xFFFF)), a0);
            a1 = fmaf(p, b2f((ushort)(v[i] >> 16)), a1);
        }
        for (int i = 8; i < n; ++i) {   // rare tail (Poisson(8): ~45% rows, few entries)
            uint2 ple = bucket[i];
            float p = __uint_as_float(ple.y);
            uint ve = xw[((size_t)(ple.x >> 20) * NIN + (ple.x & 0xFFFFF)) * 64 + lane];
            a0 = fmaf(p, b2f((ushort)(ve & 0xFFFF)), a0);
            a1 = fmaf(p, b2f((ushort)(ve >> 16)), a1);
        }
        hw[((size_t)b * NOUT + r) * 64 + c2] = pk2(a0, a1);
        float y0 = a0 + bdv.x, y1 = a1 + bdv.y;
        sA += y0 + y1; qA += y0 * y0 + y1 * y1;
    }
    #pragma unroll
    for (int o = 1; o <= 2; o <<= 1) { sA += __shfl_xor(sA, o); qA += __shfl_xor(qA, o); }
    __shared__ float red[4][2][8][2];
    if ((lane & 3) == 0) {
        red[wv][b][c2 >> 2][0] = sA;
        red[wv][b][c2 >> 2][1] = qA;
    }
    __syncthreads();
    if (tid < 32) {
        int bb = tid >> 4, g = (tid >> 1) & 7, isq = tid & 1;
        float v = red[0][bb][g][isq] + red[1][bb][g][isq] + red[2][bb][g][isq] + red[3][bb][g][isq];
        atomicAdd(&s1[(bb * 8 + g) * 2 + isq], v);
    }
}

// ---------------- kApply1: GN1 + GELU in place (bf16 h); fused GN2 stats groups 0..3 ---------
#define AGRID 2048
__global__ __launch_bounds__(256) void kApply1(ushort* __restrict__ h16, const float* __restrict__ bd,
                                               const float* __restrict__ g1, const float* __restrict__ b1,
                                               const float* __restrict__ s1, float* __restrict__ s2) {
    int tid = threadIdx.x;
    int c8g = tid & 7;
    int lane = tid & 63, wv = tid >> 6;
    const float invc = 1.0f / (8.0f * NOUT);
    float mu0 = s1[c8g * 2] * invc;
    float r0 = rsqrtf(s1[c8g * 2 + 1] * invc - mu0 * mu0 + EPS_);
    float mu1 = s1[(8 + c8g) * 2] * invc;
    float r1 = rsqrtf(s1[(8 + c8g) * 2 + 1] * invc - mu1 * mu1 + EPS_);
    float bdv[8], g1v[8], b1v[8];
    #pragma unroll
    for (int j = 0; j < 8; ++j) {
        int c = c8g * 8 + j;
        bdv[j] = bd[c]; g1v[j] = g1[c]; b1v[j] = b1[c];
    }
    float sA[2] = {0.f, 0.f}, qA[2] = {0.f, 0.f};
    const size_t total = (size_t)B_ * NOUT * 8;
    uint4* hb = reinterpret_cast<uint4*>(h16);
    for (size_t idx = (size_t)blockIdx.x * 256 + tid; idx < total; idx += (size_t)AGRID * 256) {
        size_t pn = idx >> 3;
        int b = pn >= (size_t)NOUT;
        float mu = b ? mu1 : mu0, rstd = b ? r1 : r0;
        uint4* p = hb + pn * 16 + c8g;
        uint4 hv = *p;
        const ushort* hs = reinterpret_cast<const ushort*>(&hv);
        float ls = 0.f, lq = 0.f;
        uint outw[4];
        #pragma unroll
        for (int jp = 0; jp < 4; ++jp) {
            float a0 = b2f(hs[jp * 2]) + bdv[jp * 2];
            float a1 = b2f(hs[jp * 2 + 1]) + bdv[jp * 2 + 1];
            float t0 = (a0 - mu) * rstd * g1v[jp * 2] + b1v[jp * 2];
            float t1 = (a1 - mu) * rstd * g1v[jp * 2 + 1] + b1v[jp * 2 + 1];
            float ge0 = t0 * 0.5f * (1.0f + erff(t0 * 0.70710678118654752f));
            float ge1 = t1 * 0.5f * (1.0f + erff(t1 * 0.70710678118654752f));
            ls += ge0 + ge1; lq += ge0 * ge0 + ge1 * ge1;
            outw[jp] = pk2(ge0, ge1);
        }
        sA[b] += ls; qA[b] += lq;
        uint4 st = {outw[0], outw[1], outw[2], outw[3]};
        *p = st;
    }
    #pragma unroll
    for (int o = 8; o <= 32; o <<= 1) {
        sA[0] += __shfl_xor(sA[0], o); qA[0] += __shfl_xor(qA[0], o);
        sA[1] += __shfl_xor(sA[1], o); qA[1] += __shfl_xor(qA[1], o);
    }
    sA[0] += __shfl_xor(sA[0], 1); qA[0] += __shfl_xor(qA[0], 1);
    sA[1] += __shfl_xor(sA[1], 1); qA[1] += __shfl_xor(qA[1], 1);
    __shared__ float red[4][4][4];
    if (lane < 8 && !(lane & 1)) {
        int g = lane >> 1;
        red[wv][g][0] = sA[0]; red[wv][g][1] = qA[0];
        red[wv][g][2] = sA[1]; red[wv][g][3] = qA[1];
    }
    __syncthreads();
    if (tid < 16) {
        int g = tid >> 2, q = tid & 3;
        float v = red[0][g][q] + red[1][g][q] + red[2][g][q] + red[3][g][q];
        int b = q >> 1, isq = q & 1;
        atomicAdd(&s2[(b * 8 + g) * 2 + isq], v);
    }
}

// ---------------- kQKV: one h pass (bf16), swizzled LDS, 3 output chunks ---------------------
__global__ __launch_bounds__(256) void kQKV(const ushort* __restrict__ h16, const ushort* __restrict__ wqt,
                                            const float* __restrict__ bqkv, const float* __restrict__ g2,
                                            const float* __restrict__ b2, const float* __restrict__ s2,
                                            ushort* __restrict__ qg, ushort* __restrict__ kg,
                                            ushort* __restrict__ vtg) {
    __shared__ ushort As[128][128];
    __shared__ ushort Bs[128][128];
    __shared__ float muT[16], rsT[16], g2T[128], b2T[128];
    int tid = threadIdx.x;
    size_t r0 = (size_t)blockIdx.x * 128;
    const float invc2 = 1.0f / (16.0f * NOUT);
    if (tid < 16) {
        float mu = s2[tid * 2] * invc2;
        float ex2 = s2[tid * 2 + 1] * invc2;
        muT[tid] = mu;
        rsT[tid] = rsqrtf(ex2 - mu * mu + EPS_);
    }
    if (tid < 128) { g2T[tid] = g2[tid]; b2T[tid] = b2[tid]; }
    __syncthreads();
    const uint4* hb = reinterpret_cast<const uint4*>(h16);
    for (int i = tid; i < 2048; i += 256) {
        int rl = i >> 4, c8 = i & 15;
        size_t rg = r0 + rl;
        uint4 wv = {0, 0, 0, 0};
        if (rg < PTOT) {
            int c = c8 * 8;
            int g = ((rg >= (size_t)NOUT) ? 8 : 0) + (c >> 4);
            float mu = muT[g], rs = rsT[g];
            uint4 hv = hb[rg * 16 + c8];
            const ushort* hs = reinterpret_cast<const ushort*>(&hv);
            float t[8];
            #pragma unroll
            for (int j = 0; j < 8; ++j)
                t[j] = (b2f(hs[j]) - mu) * rs * g2T[c + j] + b2T[c + j];
            wv.x = pk2(t[0], t[1]); wv.y = pk2(t[2], t[3]);
            wv.z = pk2(t[4], t[5]); wv.w = pk2(t[6], t[7]);
        }
        *reinterpret_cast<uint4*>(&As[rl][(c8 ^ (rl & 7)) * 8]) = wv;
    }
    int w = tid >> 6, lane = tid & 63;
    int l16 = lane & 15, kh = lane >> 4;
    int sa = l16 & 7;
    for (int n0 = 0; n0 < 384; n0 += 128) {
        __syncthreads();
        for (int i = tid; i < 2048; i += 256) {
            int rl = i >> 4, c8 = i & 15;
            uint4 v = *reinterpret_cast<const uint4*>(wqt + ((size_t)(n0 + rl) << 7) + c8 * 8);
            *reinterpret_cast<uint4*>(&Bs[rl][(c8 ^ (rl & 7)) * 8]) = v;
        }
        __syncthreads();
        f32x4v acc[2][8];
        #pragma unroll
        for (int mi = 0; mi < 2; ++mi)
            #pragma unroll
            for (int nf = 0; nf < 8; ++nf) { acc[mi][nf][0] = 0; acc[mi][nf][1] = 0; acc[mi][nf][2] = 0; acc[mi][nf][3] = 0; }
        #pragma unroll
        for (int ks = 0; ks < 4; ++ks) {
            int c8 = ks * 4 + kh;
            s16x8 a0 = *reinterpret_cast<const s16x8*>(&As[w * 32 + l16][(c8 ^ sa) * 8]);
            s16x8 a1 = *reinterpret_cast<const s16x8*>(&As[w * 32 + 16 + l16][(c8 ^ sa) * 8]);
            #pragma unroll
            for (int nf = 0; nf < 8; ++nf) {
                int nn = nf * 16 + l16;
                s16x8 bf = *reinterpret_cast<const s16x8*>(&Bs[nn][(c8 ^ (nn & 7)) * 8]);
                acc[0][nf] = __builtin_amdgcn_mfma_f32_16x16x32_bf16(a0, bf, acc[0][nf], 0, 0, 0);
                acc[1][nf] = __builtin_amdgcn_mfma_f32_16x16x32_bf16(a1, bf, acc[1][nf], 0, 0, 0);
            }
        }
        if (n0 < 256) {
            __syncthreads();
            const float bscale = (n0 == 0) ? QSCALE : 1.0f;
            #pragma unroll
            for (int mi = 0; mi < 2; ++mi) {
                #pragma unroll
                for (int nf = 0; nf < 8; ++nf) {
                    int coli = nf * 16 + l16;
                    float bias = bqkv[n0 + coli] * bscale;
                    #pragma unroll
                    for (int j = 0; j < 4; ++j) {
                        int rowl = w * 32 + mi * 16 + kh * 4 + j;
                        Bs[rowl][((coli >> 3) ^ (rowl & 7)) * 8 + (coli & 7)] = f2b(acc[mi][nf][j] + bias);
                    }
                }
            }
            __syncthreads();
            ushort* dst = (n0 == 0) ? qg : kg;
            for (int i = tid; i < 2048; i += 256) {
                int rl = i >> 4, c8 = i & 15;
                size_t rg = r0 + rl;
                if (rg < PTOT) {
                    uint4 v = *reinterpret_cast<const uint4*>(&Bs[rl][(c8 ^ (rl & 7)) * 8]);
                    *(reinterpret_cast<uint4*>(dst) + rg * 16 + c8) = v;
                }
            }
        } else {
            #pragma unroll
            for (int mi = 0; mi < 2; ++mi) {
                size_t rg0 = r0 + w * 32 + mi * 16 + kh * 4;
                if (rg0 < PTOT) {
                    int b = rg0 >= (size_t)NOUT;
                    size_t n = rg0 - (size_t)b * NOUT;
                    #pragma unroll
                    for (int nf = 0; nf < 8; ++nf) {
                        int coli = nf * 16 + l16;
                        float bias = bqkv[256 + coli];
                        uint2 st = { pk2(acc[mi][nf][0] + bias, acc[mi][nf][1] + bias),
                                     pk2(acc[mi][nf][2] + bias, acc[mi][nf][3] + bias) };
                        *reinterpret_cast<uint2*>(&vtg[((size_t)(b * 128 + coli)) * NOUT + n]) = st;
                    }
                }
            }
        }
    }
}

// ---------------- kAttn: V in LDS, kt-outer loop feeds BOTH q-tiles per K/V fragment ---------
__global__ __launch_bounds__(384) void kAttn(const ushort* __restrict__ qg, const ushort* __restrict__ kg,
                                             const ushort* __restrict__ vtg, ushort* __restrict__ og) {
    __shared__ ushort K_sm[360][40];   // 28.8 KB
    __shared__ ushort V_sm[32][392];   // 25.1 KB; total 53.9 KB
    int head = blockIdx.x, ring = blockIdx.y, b = blockIdx.z;
    int tid = threadIdx.x;
    size_t rowbase = (size_t)b * NOUT + (size_t)ring * 360;
    for (int i = tid; i < 1440; i += 384) {
        int r = i >> 2, c = (i & 3) * 8;
        uint4 val = *reinterpret_cast<const uint4*>(kg + (rowbase + r) * 128 + head * 32 + c);
        *reinterpret_cast<uint4*>(&K_sm[r][c]) = val;
    }
    {
        int d = tid / 12, j = tid % 12;
        const ushort* vp = vtg + ((size_t)(b * 128 + head * 32 + d)) * NOUT + (size_t)ring * 360;
        for (int c8 = j; c8 < 49; c8 += 12) {
            uint4 val = {0, 0, 0, 0};
            if (c8 < 45) val = *reinterpret_cast<const uint4*>(vp + c8 * 8);
            *reinterpret_cast<uint4*>(&V_sm[d][c8 * 8]) = val;
        }
    }
    __syncthreads();
    int wv = tid >> 6, lane = tid & 63;
    int lq = lane & 31, hi = lane >> 5;
    s16x8 qa[2], qb[2];
    bool qok[2];
    int qvv[2];
    #pragma unroll
    for (int qi = 0; qi < 2; ++qi) {
        int qt = wv + qi * 6;
        qvv[qi] = qt * 32 + lq;
        qok[qi] = qvv[qi] < 360;
        uint4 qf1 = {0, 0, 0, 0}, qf2 = {0, 0, 0, 0};
        if (qok[qi]) {
            const ushort* qp = qg + (rowbase + qvv[qi]) * 128 + head * 32;
            qf1 = *reinterpret_cast<const uint4*>(qp + hi * 8);
            qf2 = *reinterpret_cast<const uint4*>(qp + 16 + hi * 8);
        }
        qa[qi] = __builtin_bit_cast(s16x8, qf1);
        qb[qi] = __builtin_bit_cast(s16x8, qf2);
    }
    f32x16v O[2];
    #pragma unroll
    for (int qi = 0; qi < 2; ++qi)
        #pragma unroll
        for (int r2 = 0; r2 < 16; ++r2) O[qi][r2] = 0.f;
    float ls0[2] = {0.f, 0.f}, ls1[2] = {0.f, 0.f};
    #pragma unroll 1
    for (int kt = 0; kt < 12; ++kt) {
        int krow = min(kt * 32 + lq, 359);
        s16x8 ka = *reinterpret_cast<const s16x8*>(&K_sm[krow][hi * 8]);
        s16x8 kb = *reinterpret_cast<const s16x8*>(&K_sm[krow][16 + hi * 8]);
        s16x8 va = *reinterpret_cast<const s16x8*>(&V_sm[lq][kt * 32 + hi * 8]);
        s16x8 vb = *reinterpret_cast<const s16x8*>(&V_sm[lq][kt * 32 + 16 + hi * 8]);
        #pragma unroll
        for (int qi = 0; qi < 2; ++qi) {
            f32x16v S;
            #pragma unroll
            for (int r2 = 0; r2 < 16; ++r2) S[r2] = 0.f;
            S = __builtin_amdgcn_mfma_f32_32x32x16_bf16(ka, qa[qi], S, 0, 0, 0);
            S = __builtin_amdgcn_mfma_f32_32x32x16_bf16(kb, qb[qi], S, 0, 0, 0);
            if (kt == 11) {
                #pragma unroll
                for (int r2 = 4; r2 < 16; ++r2) S[r2] = -1e30f;
            }
            uint pw[8];
            #pragma unroll
            for (int pr = 0; pr < 8; ++pr) {
                float e0 = __builtin_amdgcn_exp2f(S[pr * 2]);
                float e1 = __builtin_amdgcn_exp2f(S[pr * 2 + 1]);
                pw[pr] = pk2(e0, e1);
                if (pr & 1) ls1[qi] += e0 + e1; else ls0[qi] += e0 + e1;
            }
            i32x2v r01 = __builtin_amdgcn_permlane32_swap((int)pw[0], (int)pw[2], false, false);
            i32x2v r11 = __builtin_amdgcn_permlane32_swap((int)pw[1], (int)pw[3], false, false);
            i32x2v r21 = __builtin_amdgcn_permlane32_swap((int)pw[4], (int)pw[6], false, false);
            i32x2v r31 = __builtin_amdgcn_permlane32_swap((int)pw[5], (int)pw[7], false, false);
            uint4 pf1u = {(uint)r01[0], (uint)r11[0], (uint)r01[1], (uint)r11[1]};
            uint4 pf2u = {(uint)r21[0], (uint)r31[0], (uint)r21[1], (uint)r31[1]};
            O[qi] = __builtin_amdgcn_mfma_f32_32x32x16_bf16(va, __builtin_bit_cast(s16x8, pf1u), O[qi], 0, 0, 0);
            O[qi] = __builtin_amdgcn_mfma_f32_32x32x16_bf16(vb, __builtin_bit_cast(s16x8, pf2u), O[qi], 0, 0, 0);
        }
        __builtin_amdgcn_sched_barrier(0);
    }
    #pragma unroll
    for (int qi = 0; qi < 2; ++qi) {
        float lsum = ls0[qi] + ls1[qi];
        i32x2v sw = __builtin_amdgcn_permlane32_swap(__float_as_int(lsum), __float_as_int(lsum), false, false);
        lsum = __int_as_float(sw[0]) + __int_as_float(sw[1]);
        float inv = 1.f / lsum;
        if (qok[qi]) {
            ushort* op = og + (rowbase + qvv[qi]) * 128 + head * 32;
            #pragma unroll
            for (int g4 = 0; g4 < 4; ++g4) {
                int dbase = g4 * 8 + hi * 4;
                uint w0 = pk2(O[qi][g4 * 4 + 0] * inv, O[qi][g4 * 4 + 1] * inv);
                uint w1 = pk2(O[qi][g4 * 4 + 2] * inv, O[qi][g4 * 4 + 3] * inv);
                uint2 st = {w0, w1};
                *reinterpret_cast<uint2*>(op + dbase) = st;
            }
        }
    }
}

// ---------------- kFinal (MFMA): out[b][c][n] = (o @ wo)[n][c] + bo[c] + h[b][n][c] ----------
__global__ __launch_bounds__(256) void kFinal(const ushort* __restrict__ ob, const ushort* __restrict__ wot,
                                              const float* __restrict__ bo, const ushort* __restrict__ h16,
                                              float* __restrict__ out) {
    __shared__ ushort AB[2][128][128];
    int tid = threadIdx.x;
    size_t r0 = (size_t)blockIdx.x * 128;
    for (int i = tid; i < 2048; i += 256) {
        int rl = i >> 4, c8 = i & 15;
        size_t rg = r0 + rl;
        uint4 v = {0, 0, 0, 0};
        if (rg < PTOT) v = *reinterpret_cast<const uint4*>(ob + (rg << 7) + c8 * 8);
        *reinterpret_cast<uint4*>(&AB[0][rl][(c8 ^ (rl & 7)) * 8]) = v;
    }
    for (int i = tid; i < 2048; i += 256) {
        int rl = i >> 4, c8 = i & 15;
        uint4 v = *reinterpret_cast<const uint4*>(wot + ((size_t)rl << 7) + c8 * 8);
        *reinterpret_cast<uint4*>(&AB[1][rl][(c8 ^ (rl & 7)) * 8]) = v;
    }
    __syncthreads();
    int w = tid >> 6, lane = tid & 63;
    int l16 = lane & 15, kh = lane >> 4;
    int sa = l16 & 7;
    f32x4v acc[2][8];
    #pragma unroll
    for (int mi = 0; mi < 2; ++mi)
        #pragma unroll
        for (int nf = 0; nf < 8; ++nf) { acc[mi][nf][0] = 0; acc[mi][nf][1] = 0; acc[mi][nf][2] = 0; acc[mi][nf][3] = 0; }
    #pragma unroll
    for (int ks = 0; ks < 4; ++ks) {
        int c8 = ks * 4 + kh;
        s16x8 a0 = *reinterpret_cast<const s16x8*>(&AB[0][w * 32 + l16][(c8 ^ sa) * 8]);
        s16x8 a1 = *reinterpret_cast<const s16x8*>(&AB[0][w * 32 + 16 + l16][(c8 ^ sa) * 8]);
        #pragma unroll
        for (int nf = 0; nf < 8; ++nf) {
            int nn = nf * 16 + l16;
            s16x8 bf = *reinterpret_cast<const s16x8*>(&AB[1][nn][(c8 ^ (nn & 7)) * 8]);
            acc[0][nf] = __builtin_amdgcn_mfma_f32_16x16x32_bf16(a0, bf, acc[0][nf], 0, 0, 0);
            acc[1][nf] = __builtin_amdgcn_mfma_f32_16x16x32_bf16(a1, bf, acc[1][nf], 0, 0, 0);
        }
    }
    float* trf = reinterpret_cast<float*>(&AB[0][0][0]);
    const uint* h32 = reinterpret_cast<const uint*>(h16);
    int hw = w >> 1;
    for (int half = 0; half < 2; ++half) {
        __syncthreads();
        if (hw == half) {
            #pragma unroll
            for (int mi = 0; mi < 2; ++mi) {
                #pragma unroll
                for (int nf = 0; nf < 8; ++nf) {
                    int coli = nf * 16 + l16;
                    float bv = bo[coli];
                    #pragma unroll
                    for (int j = 0; j < 4; ++j) {
                        int relrow = (w & 1) * 32 + mi * 16 + kh * 4 + j;
                        trf[relrow * 129 + coli] = acc[mi][nf][j] + bv;
                    }
                }
            }
        }
        __syncthreads();
        for (int i = tid; i < 4096; i += 256) {
            int rl = i >> 6, c2 = i & 63;
            size_t p = r0 + half * 64 + rl;
            if (p < PTOT) {
                uint hv = h32[p * 64 + c2];
                trf[rl * 129 + c2 * 2]     += b2f((ushort)(hv & 0xFFFF));
                trf[rl * 129 + c2 * 2 + 1] += b2f((ushort)(hv >> 16));
            }
        }
        __syncthreads();
        for (int i = tid; i < 8192; i += 256) {
            int c = i >> 6, rl = i & 63;
            size_t p = r0 + half * 64 + rl;
            if (p < PTOT) {
                int b = p >= (size_t)NOUT;
                size_t n = p - (size_t)b * NOUT;
                out[((size_t)(b * 128 + c)) * NOUT + n] = trf[rl * 129 + c];
            }
        }
    }
}

extern "C" void kernel_launch(void* const* d_in, const int* in_sizes, int n_in,
                              void* d_out, int out_size, void* d_ws, size_t ws_size,
                              hipStream_t stream) {
    const float* x    = (const float*)d_in[0];
    const float* skip = (const float*)d_in[1];
    const float* wd   = (const float*)d_in[2];
    const float* bd   = (const float*)d_in[3];
    const float* psi  = (const float*)d_in[4];
    const float* quad = (const float*)d_in[5];
    const float* g1   = (const float*)d_in[6];
    const float* b1   = (const float*)d_in[7];
    const float* g2   = (const float*)d_in[8];
    const float* b2   = (const float*)d_in[9];
    const float* wqkv = (const float*)d_in[10];
    const float* bqkv = (const float*)d_in[11];
    const float* wo   = (const float*)d_in[12];
    const float* bo   = (const float*)d_in[13];
    const int* row    = (const int*)d_in[14];
    const int* col    = (const int*)d_in[15];
    const int* ker    = (const int*)d_in[16];
    float* ws = (float*)d_ws;
    ushort* xw = (ushort*)ws;                // phase 1: bf16 [K][NIN][B][64]
    ushort* h16 = (ushort*)(ws + OFF_H);     // bf16 [PTOT][128]
    float* s1 = ws + OFF_S1;
    float* s2 = ws + OFF_S2;
    ushort* wtb = (ushort*)(ws + OFF_WT);
    int*   cnt = (int*)(ws + OFF_CNT);
    uint2* csr = (uint2*)(ws + OFF_CSR);
    ushort* qb  = (ushort*)(ws + OFF_Q);
    ushort* kb  = (ushort*)(ws + OFF_K);
    ushort* vtb = (ushort*)(ws + OFF_VT);
    ushort* wot = (ushort*)(ws + OFF_WOT);
    ushort* wqt = (ushort*)d_out;            // scratch: fully overwritten by kFinal
    float* out = (float*)d_out;

    hipMemsetAsync(s1, 0, 64 * sizeof(float), stream);      // s1 + s2
    hipMemsetAsync(cnt, 0, 65536 * sizeof(int), stream);

    kT<<<544, 256, 0, stream>>>(wd, wqkv, wo, wtb, wqt, wot);
    kAF<<<FILL_BASE + 2037, 256, 0, stream>>>(x, wtb, quad, xw, row, col, ker, psi, cnt, csr,
                                              skip, h16, s2);
    kGather<<<GGRID, 256, 0, stream>>>((const uint*)xw, cnt, csr, h16, bd, s1);
    kApply1<<<AGRID, 256, 0, stream>>>(h16, bd, g1, b1, s1, s2);
    kQKV<<<(int)((PTOT + 127) / 128), 256, 0, stream>>>(h16, wqt, bqkv, g2, b2, s2, qb, kb, vtb);
    kAttn<<<dim3(NH, HOUT, B_), 384, 0, stream>>>(qb, kb, vtb, qb /*o aliases q*/);
    kFinal<<<(int)((PTOT + 127) / 128), 256, 0, stream>>>(qb, wot, bo, h16, out);
}